// Round 4
// baseline (451.943 us; speedup 1.0000x reference)
//
#include <hip/hip_runtime.h>
#include <cstdint>
#include <cstddef>

// ---------- types & helpers ----------
typedef __attribute__((ext_vector_type(8))) short bfr8;   // 8 bf16 = 4 VGPRs
typedef __attribute__((ext_vector_type(4))) float acc4;   // MFMA accumulator

__device__ __forceinline__ float bf2f(short s) {
  return __uint_as_float(((unsigned)(unsigned short)s) << 16);
}
__device__ __forceinline__ short f2bf(float f) {
  unsigned u = __float_as_uint(f);
  u += 0x7fffu + ((u >> 16) & 1u);   // round-to-nearest-even
  return (short)(u >> 16);
}
// fast tanh-approx GELU
__device__ __forceinline__ float gelu_f(float x) {
  float z = 0.7978845608028654f * (x + 0.044715f * x * x * x);
  z = fminf(fmaxf(z, -12.f), 12.f);
  float e = __expf(2.f * z);
  float th = (e - 1.f) / (e + 1.f);
  return 0.5f * x * (1.f + th);
}
// async global->LDS, 16B per lane; lds dest = wave-uniform base + lane*16
__device__ __forceinline__ void load_lds16(const short* g, short* l) {
  __builtin_amdgcn_global_load_lds(
      (const __attribute__((address_space(1))) void*)g,
      (__attribute__((address_space(3))) void*)l, 16, 0, 0);
}

// Problem constants
#define BB 2
#define SS 4096
#define DD 768
#define HH 12
#define BLKSZ 64
#define NBLK 64
#define HDIM 64

// ---------- merged weight prep: 6 transposes (fp32[K][N] -> bf16[N][K]) + bias concat ----------
__global__ __launch_bounds__(256) void prep_weights(
    const float* __restrict__ wq, const float* __restrict__ wk,
    const float* __restrict__ wv, const float* __restrict__ wo,
    const float* __restrict__ w1, const float* __restrict__ w2,
    const float* __restrict__ bq, const float* __restrict__ bk,
    const float* __restrict__ bv, float* __restrict__ bqkv,
    short* __restrict__ wqT, short* __restrict__ wkT, short* __restrict__ wvT,
    short* __restrict__ woT, short* __restrict__ w1T, short* __restrict__ w2T) {
  int id = blockIdx.x;
  if (id >= 6912) {  // bias concat, 9 blocks x 256 = 2304
    int t = (id - 6912) * 256 + threadIdx.x;
    bqkv[t] = (t < 768) ? bq[t] : (t < 1536) ? bk[t - 768] : bv[t - 1536];
    return;
  }
  const float* src; short* dst; int K, N, n0, k0;
  if (id < 2304) {
    int seg = id / 576, local = id % 576;
    K = 768; N = 768;
    n0 = (local % 24) * 32; k0 = (local / 24) * 32;
    src = seg == 0 ? wq : seg == 1 ? wk : seg == 2 ? wv : wo;
    dst = seg == 0 ? wqT : seg == 1 ? wkT : seg == 2 ? wvT : woT;
  } else if (id < 4608) {
    int local = id - 2304;
    K = 768; N = 3072;
    n0 = (local % 96) * 32; k0 = (local / 96) * 32;
    src = w1; dst = w1T;
  } else {
    int local = id - 4608;
    K = 3072; N = 768;
    n0 = (local % 24) * 32; k0 = (local / 24) * 32;
    src = w2; dst = w2T;
  }
  __shared__ float tile[32][33];
  int tx = threadIdx.x & 31, ty = threadIdx.x >> 5;  // ty in 0..7
#pragma unroll
  for (int i = 0; i < 4; i++) {
    int kk = ty + i * 8;
    tile[kk][tx] = src[(size_t)(k0 + kk) * N + n0 + tx];
  }
  __syncthreads();
#pragma unroll
  for (int i = 0; i < 4; i++) {
    int nn = ty + i * 8;
    dst[(size_t)(n0 + nn) * K + k0 + tx] = f2bf(tile[tx][nn]);
  }
}

// ---------- transpose bf16 [B][S][D] -> [B][D][S] ----------
__global__ __launch_bounds__(256) void transpose_bf16(
    const short* __restrict__ src, short* __restrict__ dst) {
  __shared__ short tile[32][33];
  int b = blockIdx.z;
  int s0 = blockIdx.x * 32, d0 = blockIdx.y * 32;
  int tx = threadIdx.x & 31, ty = threadIdx.x >> 5;  // 0..7
#pragma unroll
  for (int i = 0; i < 4; i++) {
    int ss = ty + i * 8;
    tile[ss][tx] = src[((size_t)b * SS + s0 + ss) * DD + d0 + tx];
  }
  __syncthreads();
#pragma unroll
  for (int i = 0; i < 4; i++) {
    int dd = ty + i * 8;
    dst[((size_t)b * DD + d0 + dd) * SS + s0 + tx] = tile[tx][dd];
  }
}

// ---------- LayerNorm: strided fp32 in -> contiguous bf16 out [rows][768] ----------
__global__ __launch_bounds__(256) void ln_kernel(
    const float* __restrict__ in, int stride, int off,
    const float* __restrict__ gam, const float* __restrict__ bet,
    short* __restrict__ out) {
  int row = blockIdx.x;
  int t = threadIdx.x;
  const float* base = in + (size_t)row * 768 * stride + off;
  float vals[3], s = 0.f, s2 = 0.f;
#pragma unroll
  for (int i = 0; i < 3; i++) {
    int d = t + 256 * i;
    float v = base[(size_t)d * stride];
    vals[i] = v; s += v; s2 += v * v;
  }
#pragma unroll
  for (int o = 32; o; o >>= 1) { s += __shfl_down(s, o); s2 += __shfl_down(s2, o); }
  __shared__ float red[8];
  int lane = t & 63, w = t >> 6;
  if (lane == 0) { red[w] = s; red[4 + w] = s2; }
  __syncthreads();
  s = red[0] + red[1] + red[2] + red[3];
  s2 = red[4] + red[5] + red[6] + red[7];
  float mean = s * (1.f / 768.f);
  float var = s2 * (1.f / 768.f) - mean * mean;
  float rstd = rsqrtf(var + 1e-6f);
#pragma unroll
  for (int i = 0; i < 3; i++) {
    int d = t + 256 * i;
    out[(size_t)row * 768 + d] = f2bf((vals[i] - mean) * rstd * gam[d] + bet[d]);
  }
}

// ---------- bf16 MFMA GEMM: 8-phase schedule (T3+T4), 256-row tile, 8 waves ----------
// BM=256 fixed, BN in {256,128}. 512 threads = 8 waves in 2(M) x 4(N).
// Wave output: 128 x BN/4.  LDS (dynamic): A dbuf 2x[256][64] + B dbuf 2x[BN][64],
// XOR-swizzled 16B granules (T2; source pre-swizzle + read XOR, rule #21).
// Per iteration (2 K-tiles: bf0=tile it, bf1=tile it+1), 8 phases; each phase:
//   { ds_read one operand half || stage one half-tile of a future K-tile }
//   sched_barrier; s_barrier; lgkmcnt(0); sched_barrier; setprio(1);
//   MFMA one C-quadrant (4 x NJ2 frags x 2 k-halves); setprio(0); barrier.
// Region safety (derived for this wave geometry):
//   consume(bf.A)=ph3/ph7-end, consume(bf.B)=ph2/ph6-end (both waves' halves);
//   stage slots: ph1:bf1.A1(t+1) ph2:bf1.B1(t+1) ph3:bf0.B0(t+2) ph4:bf0.A0
//                ph5:bf0.A1 ph6:bf0.B1 ph7:bf1.B0(t+3) ph8:bf1.A0(t+3)
//   -> every region restaged >=1 barrier after its last reader.
// Counted vmcnt (T4) ONLY at ph4/ph8: allowed outstanding = newest 2 half-tiles
//   = LA+LB gloads (4 for BN=256, 3 for BN=128); vmcnt(0) on the final iter.
// Epilogues: as before (EPI 1..6).
template <int BN, int EPI, int SWZ>
__global__ __launch_bounds__(512, 2) void gemm_8ph(
    const short* __restrict__ A, const short* __restrict__ BT,
    const float* __restrict__ bias, const float* __restrict__ xres,
    const float* __restrict__ aux, void* __restrict__ outp, int M, int N, int K) {
  constexpr int NJ = BN / 64;    // N frags per wave (4 or 2)
  constexpr int NJ2 = NJ / 2;    // frags per N-half
  constexpr int LB = BN / 128;   // gloads per B half-tile (2 or 1)
  extern __shared__ short lds[]; // A: [2][16384] ; B at 32768: [2][BN*64]
  // ---- XCD-chunked block remap (gridDim.y = 32 -> mchunk = 4; grids %8 == 0)
  int gx = gridDim.x;
  int orig = blockIdx.x + gx * blockIdx.y;
  int mchunk = gridDim.y >> 3;
  int xcd = orig & 7, l = orig >> 3;
  int mb, nb;
  if (SWZ == 0) { nb = l / mchunk; mb = xcd * mchunk + (l % mchunk); }  // m-fastest
  else          { nb = l % gx;     mb = xcd * mchunk + (l / gx); }      // n-fastest
  int m0 = mb * 256, n0 = nb * BN;
  const int t = threadIdx.x;
  const int lane = t & 63, wave = t >> 6;
  const int wm = (wave >> 2) * 128;        // 0 / 128
  const int wn = (wave & 3) * (BN / 4);    // stride 64 (BN=256) or 32
  const int quad = lane >> 4, lc = lane & 15;
  const int rsw = (lc & 7) << 4;           // read-side XOR byte offset

  // staging source (pre-swizzled granule; 512 threads cover 64 rows / call)
  const int srow = t >> 3;                 // 0..63
  const int sg = ((t & 7) ^ (srow & 7)) * 8;
  const short* Asrc = A + (size_t)(m0 + srow) * K + sg;
  const short* Bsrc = BT + (size_t)(n0 + srow) * K + sg;

  acc4 acc[8][NJ];
#pragma unroll
  for (int i = 0; i < 8; i++)
#pragma unroll
    for (int j = 0; j < NJ; j++) acc[i][j] = (acc4){0.f, 0.f, 0.f, 0.f};
  bfr8 a0[4][2], a1[4][2], b0[NJ2][2], b1[NJ2][2];

#define SA_(buf, half, c, kt) load_lds16(Asrc + ((size_t)((half)*128 + (c)*64)) * K + (size_t)(kt) * 64, \
                                         lds + (buf)*16384 + ((half)*128 + (c)*64)*64 + t*8)
#define SB_(buf, half, c, kt) load_lds16(Bsrc + ((size_t)((half)*(BN/2) + (c)*64)) * K + (size_t)(kt) * 64, \
                                         lds + 32768 + (buf)*(BN*64) + ((half)*(BN/2) + (c)*64)*64 + t*8)
#define SAH(buf, half, kt) do { SA_(buf, half, 0, kt); SA_(buf, half, 1, kt); } while (0)
#define SBH(buf, half, kt) do { SB_(buf, half, 0, kt); if (LB == 2) SB_(buf, half, 1, kt); } while (0)
#define RA_(arr, buf, half) \
  _Pragma("unroll") for (int i_ = 0; i_ < 4; i_++) \
  _Pragma("unroll") for (int k_ = 0; k_ < 2; k_++) \
    arr[i_][k_] = *(const bfr8*)((const char*)lds + (buf)*32768 + \
        (wm + (half)*64 + i_*16 + lc)*128 + (((k_<<6)|(quad<<4)) ^ rsw))
#define RB_(arr, buf, half) \
  _Pragma("unroll") for (int j_ = 0; j_ < NJ2; j_++) \
  _Pragma("unroll") for (int k_ = 0; k_ < 2; k_++) \
    arr[j_][k_] = *(const bfr8*)((const char*)lds + 65536 + (buf)*(BN*128) + \
        (wn + (half)*(NJ2*16) + j_*16 + lc)*128 + (((k_<<6)|(quad<<4)) ^ rsw))
#define MM_(aarr, barr, i0, j0) \
  _Pragma("unroll") for (int i_ = 0; i_ < 4; i_++) \
  _Pragma("unroll") for (int j_ = 0; j_ < NJ2; j_++) \
  _Pragma("unroll") for (int k_ = 0; k_ < 2; k_++) \
    acc[(i0)+i_][(j0)+j_] = __builtin_amdgcn_mfma_f32_16x16x32_bf16( \
        aarr[i_][k_], barr[j_][k_], acc[(i0)+i_][(j0)+j_], 0, 0, 0)
#define SB0_ __builtin_amdgcn_sched_barrier(0)
#define BAR_ __builtin_amdgcn_s_barrier()
#define PH_OPEN do { SB0_; BAR_; \
    asm volatile("s_waitcnt lgkmcnt(0)" ::: "memory"); SB0_; \
    __builtin_amdgcn_s_setprio(1); } while (0)
#define PH_CLOSE do { __builtin_amdgcn_s_setprio(0); SB0_; } while (0)
#define VM_CNT do { if constexpr (LB == 2) asm volatile("s_waitcnt vmcnt(4)" ::: "memory"); \
                    else                   asm volatile("s_waitcnt vmcnt(3)" ::: "memory"); \
                    SB0_; } while (0)
#define VM_ZERO do { asm volatile("s_waitcnt vmcnt(0)" ::: "memory"); SB0_; } while (0)

  const int nk = K >> 6;  // always even (12 or 48)
  // prologue: tile 0 complete into bf0; tile 1's B0+A0 into bf1 (steady-state lag)
  SAH(0, 0, 0); SAH(0, 1, 0); SBH(0, 0, 0); SBH(0, 1, 0);
  SBH(1, 0, 1); SAH(1, 0, 1);
  VM_CNT;  // allow bf1's 2 staged halves outstanding; bf0 fully landed
  BAR_;

  for (int it = 0; it < nk; it += 2) {
    const bool more = (it + 2) < nk;
    // ph1: Q(M0,N0) of bf0 | stage bf1.A1 (tile it+1)
    RA_(a0, 0, 0); RB_(b0, 0, 0); SAH(1, 1, it + 1);
    PH_OPEN; MM_(a0, b0, 0, 0); PH_CLOSE; BAR_;
    // ph2: Q(M0,N1) | stage bf1.B1 (tile it+1)
    RB_(b1, 0, 1); SBH(1, 1, it + 1);
    PH_OPEN; MM_(a0, b1, 0, NJ2); PH_CLOSE; BAR_;
    // ph3: Q(M1,N0) | stage bf0.B0 (tile it+2)
    RA_(a1, 0, 1); if (more) SBH(0, 0, it + 2);
    PH_OPEN; MM_(a1, b0, 4, 0); PH_CLOSE; BAR_;
    // ph4: Q(M1,N1) | stage bf0.A0 ; counted vmcnt gate for bf1 reads
    if (more) SAH(0, 0, it + 2);
    PH_OPEN; MM_(a1, b1, 4, NJ2); PH_CLOSE;
    if (more) { VM_CNT; } else { VM_ZERO; }
    BAR_;
    // ph5: Q(M0,N0) of bf1 | stage bf0.A1
    RA_(a0, 1, 0); RB_(b0, 1, 0); if (more) SAH(0, 1, it + 2);
    PH_OPEN; MM_(a0, b0, 0, 0); PH_CLOSE; BAR_;
    // ph6: Q(M0,N1) | stage bf0.B1
    RB_(b1, 1, 1); if (more) SBH(0, 1, it + 2);
    PH_OPEN; MM_(a0, b1, 0, NJ2); PH_CLOSE; BAR_;
    // ph7: Q(M1,N0) | stage bf1.B0 (tile it+3)
    RA_(a1, 1, 1); if (more) SBH(1, 0, it + 3);
    PH_OPEN; MM_(a1, b0, 4, 0); PH_CLOSE; BAR_;
    // ph8: Q(M1,N1) | stage bf1.A0 (tile it+3) ; counted vmcnt gate for next ph1
    if (more) SAH(1, 0, it + 3);
    PH_OPEN; MM_(a1, b1, 4, NJ2); PH_CLOSE;
    if (more) { VM_CNT; }
    BAR_;
  }
#undef SA_
#undef SB_
#undef SAH
#undef SBH
#undef RA_
#undef RB_
#undef MM_
#undef PH_OPEN
#undef PH_CLOSE
#undef VM_CNT
#undef VM_ZERO
#undef SB0_
#undef BAR_

  // epilogue: C/D layout col=lane&15, row=(lane>>4)*4+reg
#pragma unroll
  for (int i = 0; i < 8; i++) {
#pragma unroll
    for (int j = 0; j < NJ; j++) {
      int col = n0 + wn + j * 16 + lc;
      float bv = bias[col];
#pragma unroll
      for (int r = 0; r < 4; r++) {
        int row = m0 + wm + i * 16 + quad * 4 + r;
        float v = acc[i][j][r] + bv;
        size_t idx = (size_t)row * N + col;
        if (EPI == 1) {
          v += xres[idx * 2];
          ((float*)outp)[idx * 2 + 1] = v;
        } else if (EPI == 2) {
          ((short*)outp)[idx] = f2bf(gelu_f(v));
        } else if (EPI == 3) {
          v += xres[idx * 2 + 1];
          ((float*)outp)[idx * 2] = v;
        } else if (EPI == 4) {  // QKV split (N=2304; 16-col group never straddles 768)
          int bufidx = col / 768;
          int colm = col - bufidx * 768;
          ((short*)outp)[(size_t)bufidx * 6291456 + (size_t)row * 768 + colm] = f2bf(v);
        } else if (EPI == 5) {  // y2 contiguous fp32
          v += xres[idx * 2];
          ((float*)outp)[idx] = v;
        } else {  // EPI 6: write both halves, full-line float2
          v += xres[idx * 2 + 1];
          float2 pr; pr.x = v; pr.y = aux[idx];
          ((float2*)outp)[idx] = pr;
        }
      }
    }
  }
}

// ---------- MFMA attention core ----------
__device__ __forceinline__ void attn_core(
    const short* __restrict__ qrow0, const short* __restrict__ kbase,
    const short* __restrict__ vt_h, const int* kblist, int nch, int t,
    short (*QPs)[72], short (*Ks)[72], short (*Vts)[72],
    float* m, float* l, acc4* O) {
  int lane = t & 63, w = t >> 6, quad = lane >> 4, lc = lane & 15;
#pragma unroll
  for (int c = t; c < 512; c += 256) {
    int r = c >> 3, dc = c & 7;
    *(bfr8*)&QPs[r][dc * 8] = *(const bfr8*)&qrow0[(size_t)r * DD + dc * 8];
  }
  __syncthreads();
  bfr8 aq0 = *(const bfr8*)&QPs[w * 16 + lc][quad * 8];
  bfr8 aq1 = *(const bfr8*)&QPs[w * 16 + lc][32 + quad * 8];
#pragma unroll
  for (int r = 0; r < 4; r++) { m[r] = -1e30f; l[r] = 0.f; }
#pragma unroll
  for (int dt = 0; dt < 4; dt++) O[dt] = (acc4){0.f, 0.f, 0.f, 0.f};

  for (int ch = 0; ch < nch; ch++) {
    int kb = kblist[ch];
    __syncthreads();
#pragma unroll
    for (int c = t; c < 512; c += 256) {
      int r = c >> 3, dc = c & 7;
      *(bfr8*)&Ks[r][dc * 8] = *(const bfr8*)&kbase[((size_t)kb * 64 + r) * DD + dc * 8];
      *(bfr8*)&Vts[r][dc * 8] = *(const bfr8*)&vt_h[(size_t)r * SS + kb * 64 + dc * 8];
    }
    __syncthreads();
    acc4 sacc[4];
#pragma unroll
    for (int nt = 0; nt < 4; nt++) {
      bfr8 bk0 = *(const bfr8*)&Ks[nt * 16 + lc][quad * 8];
      bfr8 bk1 = *(const bfr8*)&Ks[nt * 16 + lc][32 + quad * 8];
      acc4 z = (acc4){0.f, 0.f, 0.f, 0.f};
      z = __builtin_amdgcn_mfma_f32_16x16x32_bf16(aq0, bk0, z, 0, 0, 0);
      z = __builtin_amdgcn_mfma_f32_16x16x32_bf16(aq1, bk1, z, 0, 0, 0);
      sacc[nt] = z;
    }
#pragma unroll
    for (int r = 0; r < 4; r++) {
      float sv[4];
#pragma unroll
      for (int nt = 0; nt < 4; nt++) sv[nt] = sacc[nt][r] * 0.125f;
      float cm = fmaxf(fmaxf(sv[0], sv[1]), fmaxf(sv[2], sv[3]));
      cm = fmaxf(cm, __shfl_xor(cm, 1));
      cm = fmaxf(cm, __shfl_xor(cm, 2));
      cm = fmaxf(cm, __shfl_xor(cm, 4));
      cm = fmaxf(cm, __shfl_xor(cm, 8));
      float mn = fmaxf(m[r], cm);
      float al = __expf(m[r] - mn);
      m[r] = mn;
      float ls = 0.f;
#pragma unroll
      for (int nt = 0; nt < 4; nt++) {
        float p = __expf(sv[nt] - mn);
        ls += p;
        QPs[w * 16 + quad * 4 + r][nt * 16 + lc] = f2bf(p);
      }
      ls += __shfl_xor(ls, 1);
      ls += __shfl_xor(ls, 2);
      ls += __shfl_xor(ls, 4);
      ls += __shfl_xor(ls, 8);
      l[r] = l[r] * al + ls;
#pragma unroll
      for (int dt = 0; dt < 4; dt++) O[dt][r] *= al;
    }
    bfr8 ap0 = *(const bfr8*)&QPs[w * 16 + lc][quad * 8];
    bfr8 ap1 = *(const bfr8*)&QPs[w * 16 + lc][32 + quad * 8];
#pragma unroll
    for (int dt = 0; dt < 4; dt++) {
      bfr8 bv0 = *(const bfr8*)&Vts[dt * 16 + lc][quad * 8];
      bfr8 bv1 = *(const bfr8*)&Vts[dt * 16 + lc][32 + quad * 8];
      O[dt] = __builtin_amdgcn_mfma_f32_16x16x32_bf16(ap0, bv0, O[dt], 0, 0, 0);
      O[dt] = __builtin_amdgcn_mfma_f32_16x16x32_bf16(ap1, bv1, O[dt], 0, 0, 0);
    }
  }
}

// middle query blocks: n = 1..62; keys = {0, 63, n-1, n, n+1, r0, r1, r2}
__global__ __launch_bounds__(256) void attn_mid_mfma(
    const short* __restrict__ qbuf, const short* __restrict__ kbuf,
    const short* __restrict__ vtbuf, const int* __restrict__ rand_attn,
    short* __restrict__ ao) {
  int n = 1 + blockIdx.x;  // 1..62
  int h = blockIdx.y, b = blockIdx.z;
  int t = threadIdx.x, lane = t & 63, w = t >> 6, quad = lane >> 4, lc = lane & 15;
  int hoff = h * HDIM;
  size_t btok = (size_t)b * SS;
  __shared__ alignas(16) short QPs[64][72], Ks[64][72], Vts[64][72];
  int kblist[8];
  kblist[0] = 0; kblist[1] = NBLK - 1;
  kblist[2] = n - 1; kblist[3] = n; kblist[4] = n + 1;
#pragma unroll
  for (int r = 0; r < 3; r++)
    kblist[5 + r] = rand_attn[((size_t)h * 62 + (n - 1)) * 3 + r];
  float m[4], l[4]; acc4 O[4];
  attn_core(qbuf + (btok + (size_t)n * 64) * DD + hoff,
            kbuf + btok * DD + hoff,
            vtbuf + ((size_t)b * DD + hoff) * SS,
            kblist, 8, t, QPs, Ks, Vts, m, l, O);
#pragma unroll
  for (int r = 0; r < 4; r++) {
    float inv = 1.f / l[r];
    size_t tok = btok + (size_t)n * 64 + w * 16 + quad * 4 + r;
    short* op = ao + tok * DD + hoff;
#pragma unroll
    for (int dt = 0; dt < 4; dt++) op[dt * 16 + lc] = f2bf(O[dt][r] * inv);
  }
}

// global query blocks (0 and 63), split-K over 8 splits of 8 key-blocks each
__global__ __launch_bounds__(256) void attn_glb_mfma(
    const short* __restrict__ qbuf, const short* __restrict__ kbuf,
    const short* __restrict__ vtbuf, float* __restrict__ part) {
  int g = blockIdx.x & 1, s = blockIdx.x >> 1;  // grid.x = 16
  int h = blockIdx.y, b = blockIdx.z;
  int t = threadIdx.x, lane = t & 63, w = t >> 6, quad = lane >> 4, lc = lane & 15;
  int hoff = h * HDIM;
  size_t btok = (size_t)b * SS;
  int qblk = g ? (NBLK - 1) : 0;
  __shared__ alignas(16) short QPs[64][72], Ks[64][72], Vts[64][72];
  int kblist[8];
#pragma unroll
  for (int c = 0; c < 8; c++) kblist[c] = s * 8 + c;
  float m[4], l[4]; acc4 O[4];
  attn_core(qbuf + (btok + (size_t)qblk * 64) * DD + hoff,
            kbuf + btok * DD + hoff,
            vtbuf + ((size_t)b * DD + hoff) * SS,
            kblist, 8, t, QPs, Ks, Vts, m, l, O);
  float* pp = part + ((((size_t)b * HH + h) * 2 + g) * 8 + s) * 4224;
#pragma unroll
  for (int r = 0; r < 4; r++) {
    int row = w * 16 + quad * 4 + r;
#pragma unroll
    for (int dt = 0; dt < 4; dt++) pp[row * 64 + dt * 16 + lc] = O[dt][r];  // unnormalized
    if (lc == 0) {
      pp[4096 + row] = m[r];
      pp[4160 + row] = l[r];
    }
  }
}

__global__ __launch_bounds__(256) void attn_combine(
    const float* __restrict__ part, short* __restrict__ ao) {
  int g = blockIdx.x, h = blockIdx.y, b = blockIdx.z;
  int t = threadIdx.x, qrow = t >> 2, sub = t & 3;
  const float* base = part + (((size_t)b * HH + h) * 2 + g) * 8 * 4224;
  float mm[8], ll[8], M = -1e30f;
#pragma unroll
  for (int s = 0; s < 8; s++) {
    mm[s] = base[s * 4224 + 4096 + qrow];
    ll[s] = base[s * 4224 + 4160 + qrow];
    M = fmaxf(M, mm[s]);
  }
  float L = 0.f, O[16];
#pragma unroll
  for (int d = 0; d < 16; d++) O[d] = 0.f;
#pragma unroll
  for (int s = 0; s < 8; s++) {
    float w = __expf(mm[s] - M);
    L += w * ll[s];
    const float* Op = base + s * 4224 + qrow * 64 + sub * 16;
#pragma unroll
    for (int d = 0; d < 16; d++) O[d] += w * Op[d];
  }
  float inv = 1.f / L;
  int qblk = g ? (NBLK - 1) : 0;
  size_t tok = (size_t)b * SS + (size_t)qblk * BLKSZ + qrow;
  short* op = ao + tok * DD + h * HDIM + sub * 16;
#pragma unroll
  for (int d = 0; d < 16; d++) op[d] = f2bf(O[d] * inv);
}

// ---------- launch ----------
extern "C" void kernel_launch(void* const* d_in, const int* in_sizes, int n_in,
                              void* d_out, int out_size, void* d_ws, size_t ws_size,
                              hipStream_t stream) {
  (void)in_sizes; (void)n_in; (void)out_size;
  const float* x     = (const float*)d_in[0];
  const float* ln1_g = (const float*)d_in[1];
  const float* ln1_b = (const float*)d_in[2];
  const float* ln2_g = (const float*)d_in[3];
  const float* ln2_b = (const float*)d_in[4];
  const float* wq = (const float*)d_in[5];
  const float* bq = (const float*)d_in[6];
  const float* wk = (const float*)d_in[7];
  const float* bk = (const float*)d_in[8];
  const float* wv = (const float*)d_in[9];
  const float* bv = (const float*)d_in[10];
  const float* wo = (const float*)d_in[11];
  const float* bo = (const float*)d_in[12];
  const float* w1 = (const float*)d_in[13];
  const float* b1 = (const float*)d_in[14];
  const float* w2 = (const float*)d_in[15];
  const float* b2 = (const float*)d_in[16];
  const int* rand_attn = (const int*)d_in[17];
  float* out = (float*)d_out;

  short* wsb = (short*)d_ws;
  const size_t WD = 589824;    // 768*768
  const size_t WB = 2359296;   // 768*3072
  const size_t ACT = 6291456;  // 8192*768
  short* wqT = wsb;            // [2304][768] fused QKV^T (wq/wk/wv contiguous)
  short* wkT = wqT + WD;
  short* wvT = wkT + WD;
  short* woT = wvT + WD;
  short* w1T = woT + WD;   // [3072][768]
  short* w2T = w1T + WB;   // [768][3072]
  short* xln = w2T + WB;   // slot A
  short* qb  = xln + ACT;  // slot B
  short* kb  = qb + ACT;   // slot C
  short* vb  = kb + ACT;   // slot D
  short* aob = vb + ACT;   // slot E
  float* partp = (float*)(aob + ACT);  // 1,622,016 floats
  float* bqkv = partp + 1622016;       // 2304 floats
  float* y2f  = bqkv + 2304;           // 8192*768 floats = 25.2 MB (new path)
  short* vbT = xln;        // V^T overlays slot A (xln dead after QKV GEMM)
  short* h1 = xln;         // overlays A..D (4*ACT), after attention
  short* ln2b = aob;       // reuses E after out-proj consumed ao

  const size_t NEED = ((size_t)(y2f + ACT) - (size_t)d_ws);  // bytes incl. y2f
  bool big = ws_size >= NEED;

  const size_t LDS_256 = 131072;  // 128 KiB (BN=256)
  const size_t LDS_128 = 98304;   // 96 KiB  (BN=128)

  // 1) weight transpose+cast + bias concat
  prep_weights<<<6921, 256, 0, stream>>>(wq, wk, wv, wo, w1, w2, bq, bk, bv, bqkv,
                                         wqT, wkT, wvT, woT, w1T, w2T);

  // 2) LN1 on x1 (= x[...,1])
  ln_kernel<<<8192, 256, 0, stream>>>(x, 2, 1, ln1_g, ln1_b, xln);

  // 3) fused QKV projection  (K=768 -> m-fastest swizzle)
  gemm_8ph<256, 4, 0><<<dim3(9, 32), 512, LDS_256, stream>>>(
      xln, wqT, bqkv, nullptr, nullptr, qb, 8192, 2304, 768);

  // 3b) V -> V^T [B][D][S]
  transpose_bf16<<<dim3(128, 24, 2), 256, 0, stream>>>(vb, vbT);

  // 4) attention (MFMA)
  attn_mid_mfma<<<dim3(62, 12, 2), 256, 0, stream>>>(qb, kb, vbT, rand_attn, aob);
  attn_glb_mfma<<<dim3(16, 12, 2), 256, 0, stream>>>(qb, kb, vbT, partp);
  attn_combine<<<dim3(2, 12, 2), 256, 0, stream>>>(partp, aob);

  if (big) {
    // 5) out-proj + residual(x2) -> y2f contiguous fp32  (K=768 -> m-fastest)
    gemm_8ph<128, 5, 0><<<dim3(6, 32), 512, LDS_128, stream>>>(
        aob, woT, bo, x, nullptr, y2f, 8192, 768, 768);
    // 6) LN2 on y2f (contiguous)
    ln_kernel<<<8192, 256, 0, stream>>>(y2f, 1, 0, ln2_g, ln2_b, ln2b);
    // 7) MLP  (MLP1 K=768 -> m-fastest; MLP2 K=3072 -> n-fastest)
    gemm_8ph<256, 2, 0><<<dim3(12, 32), 512, LDS_256, stream>>>(
        ln2b, w1T, b1, nullptr, nullptr, h1, 8192, 3072, 768);
    gemm_8ph<128, 6, 1><<<dim3(6, 32), 512, LDS_128, stream>>>(
        h1, w2T, b2, x, y2f, out, 8192, 768, 3072);
  } else {
    // fallback: R4-equivalent interleaved path
    gemm_8ph<128, 1, 0><<<dim3(6, 32), 512, LDS_128, stream>>>(
        aob, woT, bo, x, nullptr, out, 8192, 768, 768);
    ln_kernel<<<8192, 256, 0, stream>>>((const float*)d_out, 2, 1, ln2_g, ln2_b, ln2b);
    gemm_8ph<256, 2, 0><<<dim3(12, 32), 512, LDS_256, stream>>>(
        ln2b, w1T, b1, nullptr, nullptr, h1, 8192, 3072, 768);
    gemm_8ph<128, 3, 1><<<dim3(6, 32), 512, LDS_128, stream>>>(
        h1, w2T, b2, x, nullptr, out, 8192, 768, 3072);
  }
}

// Round 5
// 451.362 us; speedup vs baseline: 1.0013x; 1.0013x over previous
//
#include <hip/hip_runtime.h>
#include <cstdint>
#include <cstddef>

// ---------- types & helpers ----------
typedef __attribute__((ext_vector_type(8))) short bfr8;   // 8 bf16 = 4 VGPRs
typedef __attribute__((ext_vector_type(4))) float acc4;   // MFMA accumulator
typedef __attribute__((ext_vector_type(4))) float f32x4;  // 16B copy unit

__device__ __forceinline__ float bf2f(short s) {
  return __uint_as_float(((unsigned)(unsigned short)s) << 16);
}
__device__ __forceinline__ short f2bf(float f) {
  unsigned u = __float_as_uint(f);
  u += 0x7fffu + ((u >> 16) & 1u);   // round-to-nearest-even
  return (short)(u >> 16);
}
// fast tanh-approx GELU
__device__ __forceinline__ float gelu_f(float x) {
  float z = 0.7978845608028654f * (x + 0.044715f * x * x * x);
  z = fminf(fmaxf(z, -12.f), 12.f);
  float e = __expf(2.f * z);
  float th = (e - 1.f) / (e + 1.f);
  return 0.5f * x * (1.f + th);
}
// async global->LDS, 16B per lane; lds dest = wave-uniform base + lane*16
__device__ __forceinline__ void load_lds16(const short* g, short* l) {
  __builtin_amdgcn_global_load_lds(
      (const __attribute__((address_space(1))) void*)g,
      (__attribute__((address_space(3))) void*)l, 16, 0, 0);
}

// Problem constants
#define BB 2
#define SS 4096
#define DD 768
#define HH 12
#define BLKSZ 64
#define NBLK 64
#define HDIM 64

// ---------- merged weight prep: 6 transposes (fp32[K][N] -> bf16[N][K]) + bias concat ----------
__global__ __launch_bounds__(256) void prep_weights(
    const float* __restrict__ wq, const float* __restrict__ wk,
    const float* __restrict__ wv, const float* __restrict__ wo,
    const float* __restrict__ w1, const float* __restrict__ w2,
    const float* __restrict__ bq, const float* __restrict__ bk,
    const float* __restrict__ bv, float* __restrict__ bqkv,
    short* __restrict__ wqT, short* __restrict__ wkT, short* __restrict__ wvT,
    short* __restrict__ woT, short* __restrict__ w1T, short* __restrict__ w2T) {
  int id = blockIdx.x;
  if (id >= 6912) {  // bias concat, 9 blocks x 256 = 2304
    int t = (id - 6912) * 256 + threadIdx.x;
    bqkv[t] = (t < 768) ? bq[t] : (t < 1536) ? bk[t - 768] : bv[t - 1536];
    return;
  }
  const float* src; short* dst; int K, N, n0, k0;
  if (id < 2304) {
    int seg = id / 576, local = id % 576;
    K = 768; N = 768;
    n0 = (local % 24) * 32; k0 = (local / 24) * 32;
    src = seg == 0 ? wq : seg == 1 ? wk : seg == 2 ? wv : wo;
    dst = seg == 0 ? wqT : seg == 1 ? wkT : seg == 2 ? wvT : woT;
  } else if (id < 4608) {
    int local = id - 2304;
    K = 768; N = 3072;
    n0 = (local % 96) * 32; k0 = (local / 96) * 32;
    src = w1; dst = w1T;
  } else {
    int local = id - 4608;
    K = 3072; N = 768;
    n0 = (local % 24) * 32; k0 = (local / 24) * 32;
    src = w2; dst = w2T;
  }
  __shared__ float tile[32][33];
  int tx = threadIdx.x & 31, ty = threadIdx.x >> 5;  // ty in 0..7
#pragma unroll
  for (int i = 0; i < 4; i++) {
    int kk = ty + i * 8;
    tile[kk][tx] = src[(size_t)(k0 + kk) * N + n0 + tx];
  }
  __syncthreads();
#pragma unroll
  for (int i = 0; i < 4; i++) {
    int nn = ty + i * 8;
    dst[(size_t)(n0 + nn) * K + k0 + tx] = f2bf(tile[tx][nn]);
  }
}

// ---------- transpose bf16 [B][S][D] -> [B][D][S] ----------
__global__ __launch_bounds__(256) void transpose_bf16(
    const short* __restrict__ src, short* __restrict__ dst) {
  __shared__ short tile[32][33];
  int b = blockIdx.z;
  int s0 = blockIdx.x * 32, d0 = blockIdx.y * 32;
  int tx = threadIdx.x & 31, ty = threadIdx.x >> 5;  // 0..7
#pragma unroll
  for (int i = 0; i < 4; i++) {
    int ss = ty + i * 8;
    tile[ss][tx] = src[((size_t)b * SS + s0 + ss) * DD + d0 + tx];
  }
  __syncthreads();
#pragma unroll
  for (int i = 0; i < 4; i++) {
    int dd = ty + i * 8;
    dst[((size_t)b * DD + d0 + dd) * SS + s0 + tx] = tile[tx][dd];
  }
}

// ---------- LayerNorm: strided fp32 in -> contiguous bf16 out [rows][768] ----------
__global__ __launch_bounds__(256) void ln_kernel(
    const float* __restrict__ in, int stride, int off,
    const float* __restrict__ gam, const float* __restrict__ bet,
    short* __restrict__ out) {
  int row = blockIdx.x;
  int t = threadIdx.x;
  const float* base = in + (size_t)row * 768 * stride + off;
  float vals[3], s = 0.f, s2 = 0.f;
#pragma unroll
  for (int i = 0; i < 3; i++) {
    int d = t + 256 * i;
    float v = base[(size_t)d * stride];
    vals[i] = v; s += v; s2 += v * v;
  }
#pragma unroll
  for (int o = 32; o; o >>= 1) { s += __shfl_down(s, o); s2 += __shfl_down(s2, o); }
  __shared__ float red[8];
  int lane = t & 63, w = t >> 6;
  if (lane == 0) { red[w] = s; red[4 + w] = s2; }
  __syncthreads();
  s = red[0] + red[1] + red[2] + red[3];
  s2 = red[4] + red[5] + red[6] + red[7];
  float mean = s * (1.f / 768.f);
  float var = s2 * (1.f / 768.f) - mean * mean;
  float rstd = rsqrtf(var + 1e-6f);
#pragma unroll
  for (int i = 0; i < 3; i++) {
    int d = t + 256 * i;
    out[(size_t)row * 768 + d] = f2bf((vals[i] - mean) * rstd * gam[d] + bet[d]);
  }
}

// ---------- 2-phase bf16 MFMA GEMM (R3-proven) for BN=128-shaped GEMMs ----------
// Tile BMxBN, 4 waves 2x2. XCD-chunked remap (T1) + counted-vmcnt dbuf (T4)
// + XOR-swizzled LDS (T2). See R3 notes.
template <int BM, int BN, int EPI, int SWZ>
__global__ __launch_bounds__(256) void gemm_lds(
    const short* __restrict__ A, const short* __restrict__ BT,
    const float* __restrict__ bias, const float* __restrict__ xres,
    const float* __restrict__ aux, void* __restrict__ outp, int M, int N, int K) {
  __shared__ alignas(16) short As[2][BM * 64];
  __shared__ alignas(16) short Bs[2][BN * 64];
  constexpr int TI = BM / 32;
  constexpr int TJ = BN / 32;
  static_assert(TI + TJ == 8, "vmcnt(8) immediate assumes 8 loads/tile/wave");
  int orig = blockIdx.x + gridDim.x * blockIdx.y;
  int gx = gridDim.x;
  int mchunk = gridDim.y >> 3;
  int xcd = orig & 7, l = orig >> 3;
  int mb, nb;
  if (SWZ == 0) { nb = l / mchunk; mb = xcd * mchunk + (l % mchunk); }
  else          { nb = l % gx;     mb = xcd * mchunk + (l / gx); }
  int m0 = mb * BM, n0 = nb * BN;
  int t = threadIdx.x;
  int lane = t & 63, wave = t >> 6;
  int wm = (wave >> 1) * (BM / 2), wn = (wave & 1) * (BN / 2);
  int quad = lane >> 4, lc = lane & 15;
  acc4 acc[TI][TJ];
#pragma unroll
  for (int i = 0; i < TI; i++)
#pragma unroll
    for (int j = 0; j < TJ; j++) acc[i][j] = (acc4){0.f, 0.f, 0.f, 0.f};

  int lrow = lane >> 3;
  int scol = ((lane & 7) ^ lrow) * 8;
  const short* Ag = A + (size_t)(m0 + wave * (BM / 4) + lrow) * K + scol;
  const short* Bg = BT + (size_t)(n0 + wave * (BN / 4) + lrow) * K + scol;
  int aoff = wave * (BM * 16);
  int boff = wave * (BN * 16);
  int rsw = (lc & 7) << 4;

  const int nk = K >> 6;
#pragma unroll
  for (int j = 0; j < TI; j++)
    load_lds16(Ag + (size_t)(j * 8) * K, &As[0][aoff + j * 512]);
#pragma unroll
  for (int j = 0; j < TJ; j++)
    load_lds16(Bg + (size_t)(j * 8) * K, &Bs[0][boff + j * 512]);
  if (nk > 1) {
#pragma unroll
    for (int j = 0; j < TI; j++)
      load_lds16(Ag + 64 + (size_t)(j * 8) * K, &As[1][aoff + j * 512]);
#pragma unroll
    for (int j = 0; j < TJ; j++)
      load_lds16(Bg + 64 + (size_t)(j * 8) * K, &Bs[1][boff + j * 512]);
  }

  for (int it = 0; it < nk; ++it) {
    int cur = it & 1;
    if (it + 1 < nk) asm volatile("s_waitcnt vmcnt(8)" ::: "memory");
    else             asm volatile("s_waitcnt vmcnt(0)" ::: "memory");
    __builtin_amdgcn_s_barrier();
    __builtin_amdgcn_sched_barrier(0);
    const char* Ab = (const char*)&As[cur][0];
    const char* Bb = (const char*)&Bs[cur][0];
#pragma unroll
    for (int kk = 0; kk < 2; kk++) {
      int rboff = ((kk << 6) | (quad << 4)) ^ rsw;
      bfr8 afr[TI], bfr[TJ];
#pragma unroll
      for (int i = 0; i < TI; i++)
        afr[i] = *(const bfr8*)(Ab + (wm + i * 16 + lc) * 128 + rboff);
#pragma unroll
      for (int j = 0; j < TJ; j++)
        bfr[j] = *(const bfr8*)(Bb + (wn + j * 16 + lc) * 128 + rboff);
#pragma unroll
      for (int i = 0; i < TI; i++)
#pragma unroll
        for (int j = 0; j < TJ; j++)
          acc[i][j] = __builtin_amdgcn_mfma_f32_16x16x32_bf16(afr[i], bfr[j], acc[i][j], 0, 0, 0);
    }
    if (it < nk - 2) {
      __builtin_amdgcn_sched_barrier(0);
      __builtin_amdgcn_s_barrier();
      __builtin_amdgcn_sched_barrier(0);
      int k0 = (it + 2) << 6;
#pragma unroll
      for (int j = 0; j < TI; j++)
        load_lds16(Ag + k0 + (size_t)(j * 8) * K, &As[cur][aoff + j * 512]);
#pragma unroll
      for (int j = 0; j < TJ; j++)
        load_lds16(Bg + k0 + (size_t)(j * 8) * K, &Bs[cur][boff + j * 512]);
    }
  }
  // epilogue: C/D layout col=lane&15, row=(lane>>4)*4+reg
#pragma unroll
  for (int i = 0; i < TI; i++) {
#pragma unroll
    for (int j = 0; j < TJ; j++) {
      int col = n0 + wn + j * 16 + lc;
      float bv = bias[col];
#pragma unroll
      for (int r = 0; r < 4; r++) {
        int row = m0 + wm + i * 16 + quad * 4 + r;
        float v = acc[i][j][r] + bv;
        size_t idx = (size_t)row * N + col;
        if (EPI == 1) {
          v += xres[idx * 2];
          ((float*)outp)[idx * 2 + 1] = v;
        } else if (EPI == 2) {
          ((short*)outp)[idx] = f2bf(gelu_f(v));
        } else if (EPI == 3) {
          v += xres[idx * 2 + 1];
          ((float*)outp)[idx * 2] = v;
        } else if (EPI == 4) {
          int bufidx = col / 768;
          int colm = col - bufidx * 768;
          ((short*)outp)[(size_t)bufidx * 6291456 + (size_t)row * 768 + colm] = f2bf(v);
        } else if (EPI == 5) {
          v += xres[idx * 2];
          ((float*)outp)[idx] = v;
        } else {  // EPI 6
          v += xres[idx * 2 + 1];
          float2 pr; pr.x = v; pr.y = aux[idx];
          ((float2*)outp)[idx] = pr;
        }
      }
    }
  }
}

// ---------- 8-phase bf16 MFMA GEMM (T3+T4+T5), 256-row tile, 8 waves ----------
// BM=256, BN in {256,128}. 512 threads = 8 waves 2(M) x 4(N); wave out 128 x BN/4.
// LDS dynamic: A dbuf 2x[256][64] + B dbuf 2x[BN][64], XOR-swizzled (T2).
// ONE barrier per phase: { ds_read subtile || stage half-tile -> setprio(1) MFMA
// quadrant setprio(0) -> [vm gate ph4/ph8] -> sched_barrier(0); s_barrier }.
// The SB0-before-BAR is a full scheduling fence: phase-p reads/MFMAs pinned
// above BAR_p, phase-p+1 ops pinned below -> restage of a region is always
// >=1 barrier after its last reader.  No lgkmcnt asm: compiler emits the
// fine-grained lgkm ladder for its own ds_reads (m97 evidence).
// vmcnt(LA+LB) gates only at ph4/ph8 (R4-proven accounting): drains all but
// the newest 2 half-tile stages, so the bf about to be read has fully landed.
// Epilogue (EPI 2/4): C-tile (bf16, 256xBN = 128 KiB at BN=256) restaged in
// LDS then copied out as 16B dwordx4 stores (coalesced) — replaces 128 scalar
// short stores/thread.
template <int BN, int EPI, int SWZ>
__global__ __launch_bounds__(512, 2) void gemm_8ph(
    const short* __restrict__ A, const short* __restrict__ BT,
    const float* __restrict__ bias, const float* __restrict__ xres,
    const float* __restrict__ aux, void* __restrict__ outp, int M, int N, int K) {
  constexpr int NJ = BN / 64;
  constexpr int NJ2 = NJ / 2;
  constexpr int LB = BN / 128;
  extern __shared__ short lds[];
  int gx = gridDim.x;
  int orig = blockIdx.x + gx * blockIdx.y;
  int mchunk = gridDim.y >> 3;
  int xcd = orig & 7, l = orig >> 3;
  int mb, nb;
  if (SWZ == 0) { nb = l / mchunk; mb = xcd * mchunk + (l % mchunk); }
  else          { nb = l % gx;     mb = xcd * mchunk + (l / gx); }
  int m0 = mb * 256, n0 = nb * BN;
  const int t = threadIdx.x;
  const int lane = t & 63, wave = t >> 6;
  const int wm = (wave >> 2) * 128;
  const int wn = (wave & 3) * (BN / 4);
  const int quad = lane >> 4, lc = lane & 15;
  const int rsw = (lc & 7) << 4;

  const int srow = t >> 3;
  const int sg = ((t & 7) ^ (srow & 7)) * 8;
  const short* Asrc = A + (size_t)(m0 + srow) * K + sg;
  const short* Bsrc = BT + (size_t)(n0 + srow) * K + sg;

  acc4 acc[8][NJ];
#pragma unroll
  for (int i = 0; i < 8; i++)
#pragma unroll
    for (int j = 0; j < NJ; j++) acc[i][j] = (acc4){0.f, 0.f, 0.f, 0.f};
  bfr8 a0[4][2], a1[4][2], b0[NJ2][2], b1[NJ2][2];

#define SA_(buf, half, c, kt) load_lds16(Asrc + ((size_t)((half)*128 + (c)*64)) * K + (size_t)(kt) * 64, \
                                         lds + (buf)*16384 + ((half)*128 + (c)*64)*64 + t*8)
#define SB_(buf, half, c, kt) load_lds16(Bsrc + ((size_t)((half)*(BN/2) + (c)*64)) * K + (size_t)(kt) * 64, \
                                         lds + 32768 + (buf)*(BN*64) + ((half)*(BN/2) + (c)*64)*64 + t*8)
#define SAH(buf, half, kt) do { SA_(buf, half, 0, kt); SA_(buf, half, 1, kt); } while (0)
#define SBH(buf, half, kt) do { SB_(buf, half, 0, kt); if (LB == 2) SB_(buf, half, 1, kt); } while (0)
#define RA_(arr, buf, half) \
  _Pragma("unroll") for (int i_ = 0; i_ < 4; i_++) \
  _Pragma("unroll") for (int k_ = 0; k_ < 2; k_++) \
    arr[i_][k_] = *(const bfr8*)((const char*)lds + (buf)*32768 + \
        (wm + (half)*64 + i_*16 + lc)*128 + (((k_<<6)|(quad<<4)) ^ rsw))
#define RB_(arr, buf, half) \
  _Pragma("unroll") for (int j_ = 0; j_ < NJ2; j_++) \
  _Pragma("unroll") for (int k_ = 0; k_ < 2; k_++) \
    arr[j_][k_] = *(const bfr8*)((const char*)lds + 65536 + (buf)*(BN*128) + \
        (wn + (half)*(NJ2*16) + j_*16 + lc)*128 + (((k_<<6)|(quad<<4)) ^ rsw))
#define MM_(aarr, barr, i0, j0) \
  _Pragma("unroll") for (int i_ = 0; i_ < 4; i_++) \
  _Pragma("unroll") for (int j_ = 0; j_ < NJ2; j_++) \
  _Pragma("unroll") for (int k_ = 0; k_ < 2; k_++) \
    acc[(i0)+i_][(j0)+j_] = __builtin_amdgcn_mfma_f32_16x16x32_bf16( \
        aarr[i_][k_], barr[j_][k_], acc[(i0)+i_][(j0)+j_], 0, 0, 0)
#define P1_ __builtin_amdgcn_s_setprio(1)
#define P0_ __builtin_amdgcn_s_setprio(0)
#define FENCE_BAR do { __builtin_amdgcn_sched_barrier(0); __builtin_amdgcn_s_barrier(); } while (0)
#define VM_CNT do { if constexpr (LB == 2) asm volatile("s_waitcnt vmcnt(4)" ::: "memory"); \
                    else                   asm volatile("s_waitcnt vmcnt(3)" ::: "memory"); } while (0)
#define VM_ZERO asm volatile("s_waitcnt vmcnt(0)" ::: "memory")

  const int nk = K >> 6;  // even (12 or 48)
  // prologue: tile 0 full into bf0; tile 1's B0+A0 into bf1
  SAH(0, 0, 0); SAH(0, 1, 0); SBH(0, 0, 0); SBH(0, 1, 0);
  SBH(1, 0, 1); SAH(1, 0, 1);
  VM_CNT;            // bf0 fully landed; bf1's 2 halves may fly
  FENCE_BAR;

  for (int it = 0; it < nk; it += 2) {
    const bool more = (it + 2) < nk;
    // ph1: Q(M0,N0) of bf0 | stage bf1.A1 (tile it+1)
    RA_(a0, 0, 0); RB_(b0, 0, 0); SAH(1, 1, it + 1);
    P1_; MM_(a0, b0, 0, 0); P0_; FENCE_BAR;
    // ph2: Q(M0,N1) | stage bf1.B1 (tile it+1)
    RB_(b1, 0, 1); SBH(1, 1, it + 1);
    P1_; MM_(a0, b1, 0, NJ2); P0_; FENCE_BAR;
    // ph3: Q(M1,N0) | stage bf0.B0 (tile it+2)
    RA_(a1, 0, 1); if (more) SBH(0, 0, it + 2);
    P1_; MM_(a1, b0, 4, 0); P0_; FENCE_BAR;
    // ph4: Q(M1,N1) | stage bf0.A0 ; gate: bf1 fully landed before ph5 reads
    if (more) SAH(0, 0, it + 2);
    P1_; MM_(a1, b1, 4, NJ2); P0_;
    if (more) { VM_CNT; } else { VM_ZERO; }
    FENCE_BAR;
    // ph5: Q(M0,N0) of bf1 | stage bf0.A1
    RA_(a0, 1, 0); RB_(b0, 1, 0); if (more) SAH(0, 1, it + 2);
    P1_; MM_(a0, b0, 0, 0); P0_; FENCE_BAR;
    // ph6: Q(M0,N1) | stage bf0.B1
    RB_(b1, 1, 1); if (more) SBH(0, 1, it + 2);
    P1_; MM_(a0, b1, 0, NJ2); P0_; FENCE_BAR;
    // ph7: Q(M1,N0) | stage bf1.B0 (tile it+3)
    RA_(a1, 1, 1); if (more) SBH(1, 0, it + 3);
    P1_; MM_(a1, b0, 4, 0); P0_; FENCE_BAR;
    // ph8: Q(M1,N1) | stage bf1.A0 (tile it+3) ; gate for next ph1's bf0 reads
    if (more) SAH(1, 0, it + 3);
    P1_; MM_(a1, b1, 4, NJ2); P0_;
    if (more) { VM_CNT; }
    FENCE_BAR;
  }
#undef SA_
#undef SB_
#undef SAH
#undef SBH
#undef RA_
#undef RB_
#undef MM_
#undef P1_
#undef P0_
#undef FENCE_BAR
#undef VM_CNT
#undef VM_ZERO

  if constexpr (EPI == 2 || EPI == 4) {
    // ---- coalesced epilogue: bf16 C-tile via LDS (256 x BN x 2B <= 128 KiB) ----
    short* ot = lds;
#pragma unroll
    for (int i = 0; i < 8; i++)
#pragma unroll
      for (int j = 0; j < NJ; j++) {
        int col = wn + j * 16 + lc;
        float bv = bias[n0 + col];
#pragma unroll
        for (int r = 0; r < 4; r++) {
          int row = wm + i * 16 + quad * 4 + r;
          float v = acc[i][j][r] + bv;
          if (EPI == 2) v = gelu_f(v);
          ot[row * BN + col] = f2bf(v);
        }
      }
    __syncthreads();
    constexpr int CPR = BN / 8;  // 16B chunks per row
    short* obase; int ostride;
    if (EPI == 4) {
      int bufidx = n0 / 768;     // 256-col block never straddles a 768 boundary
      obase = (short*)outp + (size_t)bufidx * 6291456 + (size_t)m0 * 768 + (n0 - bufidx * 768);
      ostride = 768;
    } else {
      obase = (short*)outp + (size_t)m0 * N + n0;
      ostride = N;
    }
#pragma unroll
    for (int q = 0; q < 256 * CPR / 512; q++) {
      int c = q * 512 + t;
      int row = c / CPR, ch = c % CPR;
      *(f32x4*)(obase + (size_t)row * ostride + ch * 8) =
          *(const f32x4*)(ot + row * BN + ch * 8);
    }
  } else {
    // generic direct epilogue (not used by current launches)
#pragma unroll
    for (int i = 0; i < 8; i++) {
#pragma unroll
      for (int j = 0; j < NJ; j++) {
        int col = n0 + wn + j * 16 + lc;
        float bv = bias[col];
#pragma unroll
        for (int r = 0; r < 4; r++) {
          int row = m0 + wm + i * 16 + quad * 4 + r;
          float v = acc[i][j][r] + bv;
          size_t idx = (size_t)row * N + col;
          if (EPI == 1) {
            v += xres[idx * 2];
            ((float*)outp)[idx * 2 + 1] = v;
          } else if (EPI == 3) {
            v += xres[idx * 2 + 1];
            ((float*)outp)[idx * 2] = v;
          } else if (EPI == 5) {
            v += xres[idx * 2];
            ((float*)outp)[idx] = v;
          } else {
            v += xres[idx * 2 + 1];
            float2 pr; pr.x = v; pr.y = aux[idx];
            ((float2*)outp)[idx] = pr;
          }
        }
      }
    }
  }
}

// ---------- MFMA attention core ----------
__device__ __forceinline__ void attn_core(
    const short* __restrict__ qrow0, const short* __restrict__ kbase,
    const short* __restrict__ vt_h, const int* kblist, int nch, int t,
    short (*QPs)[72], short (*Ks)[72], short (*Vts)[72],
    float* m, float* l, acc4* O) {
  int lane = t & 63, w = t >> 6, quad = lane >> 4, lc = lane & 15;
#pragma unroll
  for (int c = t; c < 512; c += 256) {
    int r = c >> 3, dc = c & 7;
    *(bfr8*)&QPs[r][dc * 8] = *(const bfr8*)&qrow0[(size_t)r * DD + dc * 8];
  }
  __syncthreads();
  bfr8 aq0 = *(const bfr8*)&QPs[w * 16 + lc][quad * 8];
  bfr8 aq1 = *(const bfr8*)&QPs[w * 16 + lc][32 + quad * 8];
#pragma unroll
  for (int r = 0; r < 4; r++) { m[r] = -1e30f; l[r] = 0.f; }
#pragma unroll
  for (int dt = 0; dt < 4; dt++) O[dt] = (acc4){0.f, 0.f, 0.f, 0.f};

  for (int ch = 0; ch < nch; ch++) {
    int kb = kblist[ch];
    __syncthreads();
#pragma unroll
    for (int c = t; c < 512; c += 256) {
      int r = c >> 3, dc = c & 7;
      *(bfr8*)&Ks[r][dc * 8] = *(const bfr8*)&kbase[((size_t)kb * 64 + r) * DD + dc * 8];
      *(bfr8*)&Vts[r][dc * 8] = *(const bfr8*)&vt_h[(size_t)r * SS + kb * 64 + dc * 8];
    }
    __syncthreads();
    acc4 sacc[4];
#pragma unroll
    for (int nt = 0; nt < 4; nt++) {
      bfr8 bk0 = *(const bfr8*)&Ks[nt * 16 + lc][quad * 8];
      bfr8 bk1 = *(const bfr8*)&Ks[nt * 16 + lc][32 + quad * 8];
      acc4 z = (acc4){0.f, 0.f, 0.f, 0.f};
      z = __builtin_amdgcn_mfma_f32_16x16x32_bf16(aq0, bk0, z, 0, 0, 0);
      z = __builtin_amdgcn_mfma_f32_16x16x32_bf16(aq1, bk1, z, 0, 0, 0);
      sacc[nt] = z;
    }
#pragma unroll
    for (int r = 0; r < 4; r++) {
      float sv[4];
#pragma unroll
      for (int nt = 0; nt < 4; nt++) sv[nt] = sacc[nt][r] * 0.125f;
      float cm = fmaxf(fmaxf(sv[0], sv[1]), fmaxf(sv[2], sv[3]));
      cm = fmaxf(cm, __shfl_xor(cm, 1));
      cm = fmaxf(cm, __shfl_xor(cm, 2));
      cm = fmaxf(cm, __shfl_xor(cm, 4));
      cm = fmaxf(cm, __shfl_xor(cm, 8));
      float mn = fmaxf(m[r], cm);
      float al = __expf(m[r] - mn);
      m[r] = mn;
      float ls = 0.f;
#pragma unroll
      for (int nt = 0; nt < 4; nt++) {
        float p = __expf(sv[nt] - mn);
        ls += p;
        QPs[w * 16 + quad * 4 + r][nt * 16 + lc] = f2bf(p);
      }
      ls += __shfl_xor(ls, 1);
      ls += __shfl_xor(ls, 2);
      ls += __shfl_xor(ls, 4);
      ls += __shfl_xor(ls, 8);
      l[r] = l[r] * al + ls;
#pragma unroll
      for (int dt = 0; dt < 4; dt++) O[dt][r] *= al;
    }
    bfr8 ap0 = *(const bfr8*)&QPs[w * 16 + lc][quad * 8];
    bfr8 ap1 = *(const bfr8*)&QPs[w * 16 + lc][32 + quad * 8];
#pragma unroll
    for (int dt = 0; dt < 4; dt++) {
      bfr8 bv0 = *(const bfr8*)&Vts[dt * 16 + lc][quad * 8];
      bfr8 bv1 = *(const bfr8*)&Vts[dt * 16 + lc][32 + quad * 8];
      O[dt] = __builtin_amdgcn_mfma_f32_16x16x32_bf16(ap0, bv0, O[dt], 0, 0, 0);
      O[dt] = __builtin_amdgcn_mfma_f32_16x16x32_bf16(ap1, bv1, O[dt], 0, 0, 0);
    }
  }
}

// middle query blocks: n = 1..62; keys = {0, 63, n-1, n, n+1, r0, r1, r2}
__global__ __launch_bounds__(256) void attn_mid_mfma(
    const short* __restrict__ qbuf, const short* __restrict__ kbuf,
    const short* __restrict__ vtbuf, const int* __restrict__ rand_attn,
    short* __restrict__ ao) {
  int n = 1 + blockIdx.x;  // 1..62
  int h = blockIdx.y, b = blockIdx.z;
  int t = threadIdx.x, lane = t & 63, w = t >> 6, quad = lane >> 4, lc = lane & 15;
  int hoff = h * HDIM;
  size_t btok = (size_t)b * SS;
  __shared__ alignas(16) short QPs[64][72], Ks[64][72], Vts[64][72];
  int kblist[8];
  kblist[0] = 0; kblist[1] = NBLK - 1;
  kblist[2] = n - 1; kblist[3] = n; kblist[4] = n + 1;
#pragma unroll
  for (int r = 0; r < 3; r++)
    kblist[5 + r] = rand_attn[((size_t)h * 62 + (n - 1)) * 3 + r];
  float m[4], l[4]; acc4 O[4];
  attn_core(qbuf + (btok + (size_t)n * 64) * DD + hoff,
            kbuf + btok * DD + hoff,
            vtbuf + ((size_t)b * DD + hoff) * SS,
            kblist, 8, t, QPs, Ks, Vts, m, l, O);
#pragma unroll
  for (int r = 0; r < 4; r++) {
    float inv = 1.f / l[r];
    size_t tok = btok + (size_t)n * 64 + w * 16 + quad * 4 + r;
    short* op = ao + tok * DD + hoff;
#pragma unroll
    for (int dt = 0; dt < 4; dt++) op[dt * 16 + lc] = f2bf(O[dt][r] * inv);
  }
}

// global query blocks (0 and 63), split-K over 8 splits of 8 key-blocks each
__global__ __launch_bounds__(256) void attn_glb_mfma(
    const short* __restrict__ qbuf, const short* __restrict__ kbuf,
    const short* __restrict__ vtbuf, float* __restrict__ part) {
  int g = blockIdx.x & 1, s = blockIdx.x >> 1;  // grid.x = 16
  int h = blockIdx.y, b = blockIdx.z;
  int t = threadIdx.x, lane = t & 63, w = t >> 6, quad = lane >> 4, lc = lane & 15;
  int hoff = h * HDIM;
  size_t btok = (size_t)b * SS;
  int qblk = g ? (NBLK - 1) : 0;
  __shared__ alignas(16) short QPs[64][72], Ks[64][72], Vts[64][72];
  int kblist[8];
#pragma unroll
  for (int c = 0; c < 8; c++) kblist[c] = s * 8 + c;
  float m[4], l[4]; acc4 O[4];
  attn_core(qbuf + (btok + (size_t)qblk * 64) * DD + hoff,
            kbuf + btok * DD + hoff,
            vtbuf + ((size_t)b * DD + hoff) * SS,
            kblist, 8, t, QPs, Ks, Vts, m, l, O);
  float* pp = part + ((((size_t)b * HH + h) * 2 + g) * 8 + s) * 4224;
#pragma unroll
  for (int r = 0; r < 4; r++) {
    int row = w * 16 + quad * 4 + r;
#pragma unroll
    for (int dt = 0; dt < 4; dt++) pp[row * 64 + dt * 16 + lc] = O[dt][r];  // unnormalized
    if (lc == 0) {
      pp[4096 + row] = m[r];
      pp[4160 + row] = l[r];
    }
  }
}

__global__ __launch_bounds__(256) void attn_combine(
    const float* __restrict__ part, short* __restrict__ ao) {
  int g = blockIdx.x, h = blockIdx.y, b = blockIdx.z;
  int t = threadIdx.x, qrow = t >> 2, sub = t & 3;
  const float* base = part + (((size_t)b * HH + h) * 2 + g) * 8 * 4224;
  float mm[8], ll[8], M = -1e30f;
#pragma unroll
  for (int s = 0; s < 8; s++) {
    mm[s] = base[s * 4224 + 4096 + qrow];
    ll[s] = base[s * 4224 + 4160 + qrow];
    M = fmaxf(M, mm[s]);
  }
  float L = 0.f, O[16];
#pragma unroll
  for (int d = 0; d < 16; d++) O[d] = 0.f;
#pragma unroll
  for (int s = 0; s < 8; s++) {
    float w = __expf(mm[s] - M);
    L += w * ll[s];
    const float* Op = base + s * 4224 + qrow * 64 + sub * 16;
#pragma unroll
    for (int d = 0; d < 16; d++) O[d] += w * Op[d];
  }
  float inv = 1.f / L;
  int qblk = g ? (NBLK - 1) : 0;
  size_t tok = (size_t)b * SS + (size_t)qblk * BLKSZ + qrow;
  short* op = ao + tok * DD + h * HDIM + sub * 16;
#pragma unroll
  for (int d = 0; d < 16; d++) op[d] = f2bf(O[d] * inv);
}

// ---------- launch ----------
extern "C" void kernel_launch(void* const* d_in, const int* in_sizes, int n_in,
                              void* d_out, int out_size, void* d_ws, size_t ws_size,
                              hipStream_t stream) {
  (void)in_sizes; (void)n_in; (void)out_size;
  const float* x     = (const float*)d_in[0];
  const float* ln1_g = (const float*)d_in[1];
  const float* ln1_b = (const float*)d_in[2];
  const float* ln2_g = (const float*)d_in[3];
  const float* ln2_b = (const float*)d_in[4];
  const float* wq = (const float*)d_in[5];
  const float* bq = (const float*)d_in[6];
  const float* wk = (const float*)d_in[7];
  const float* bk = (const float*)d_in[8];
  const float* wv = (const float*)d_in[9];
  const float* bv = (const float*)d_in[10];
  const float* wo = (const float*)d_in[11];
  const float* bo = (const float*)d_in[12];
  const float* w1 = (const float*)d_in[13];
  const float* b1 = (const float*)d_in[14];
  const float* w2 = (const float*)d_in[15];
  const float* b2 = (const float*)d_in[16];
  const int* rand_attn = (const int*)d_in[17];
  float* out = (float*)d_out;

  short* wsb = (short*)d_ws;
  const size_t WD = 589824;    // 768*768
  const size_t WB = 2359296;   // 768*3072
  const size_t ACT = 6291456;  // 8192*768
  short* wqT = wsb;
  short* wkT = wqT + WD;
  short* wvT = wkT + WD;
  short* woT = wvT + WD;
  short* w1T = woT + WD;   // [3072][768]
  short* w2T = w1T + WB;   // [768][3072]
  short* xln = w2T + WB;   // slot A
  short* qb  = xln + ACT;  // slot B
  short* kb  = qb + ACT;   // slot C
  short* vb  = kb + ACT;   // slot D
  short* aob = vb + ACT;   // slot E
  float* partp = (float*)(aob + ACT);
  float* bqkv = partp + 1622016;
  float* y2f  = bqkv + 2304;
  short* vbT = xln;
  short* h1 = xln;
  short* ln2b = aob;

  const size_t NEED = ((size_t)(y2f + ACT) - (size_t)d_ws);
  bool big = ws_size >= NEED;

  const size_t LDS_256 = 131072;  // 128 KiB (BN=256)

  // 1) weight transpose+cast + bias concat
  prep_weights<<<6921, 256, 0, stream>>>(wq, wk, wv, wo, w1, w2, bq, bk, bv, bqkv,
                                         wqT, wkT, wvT, woT, w1T, w2T);

  // 2) LN1 on x1 (= x[...,1])
  ln_kernel<<<8192, 256, 0, stream>>>(x, 2, 1, ln1_g, ln1_b, xln);

  // 3) fused QKV projection  (K=768 -> m-fastest swizzle)
  gemm_8ph<256, 4, 0><<<dim3(9, 32), 512, LDS_256, stream>>>(
      xln, wqT, bqkv, nullptr, nullptr, qb, 8192, 2304, 768);

  // 3b) V -> V^T [B][D][S]
  transpose_bf16<<<dim3(128, 24, 2), 256, 0, stream>>>(vb, vbT);

  // 4) attention (MFMA)
  attn_mid_mfma<<<dim3(62, 12, 2), 256, 0, stream>>>(qb, kb, vbT, rand_attn, aob);
  attn_glb_mfma<<<dim3(16, 12, 2), 256, 0, stream>>>(qb, kb, vbT, partp);
  attn_combine<<<dim3(2, 12, 2), 256, 0, stream>>>(partp, aob);

  if (big) {
    // 5) out-proj + residual(x2) -> y2f contiguous fp32  (2-phase, K=768)
    gemm_lds<128, 128, 5, 0><<<dim3(6, 64), 256, 0, stream>>>(
        aob, woT, bo, x, nullptr, y2f, 8192, 768, 768);
    // 6) LN2 on y2f (contiguous)
    ln_kernel<<<8192, 256, 0, stream>>>(y2f, 1, 0, ln2_g, ln2_b, ln2b);
    // 7) MLP  (MLP1 8-phase BN=256; MLP2 2-phase K=3072 n-fastest)
    gemm_8ph<256, 2, 0><<<dim3(12, 32), 512, LDS_256, stream>>>(
        ln2b, w1T, b1, nullptr, nullptr, h1, 8192, 3072, 768);
    gemm_lds<128, 128, 6, 1><<<dim3(6, 64), 256, 0, stream>>>(
        h1, w2T, b2, x, y2f, out, 8192, 768, 3072);
  } else {
    // fallback: R3-equivalent interleaved path (all 2-phase)
    gemm_lds<128, 128, 1, 0><<<dim3(6, 64), 256, 0, stream>>>(
        aob, woT, bo, x, nullptr, out, 8192, 768, 768);
    ln_kernel<<<8192, 256, 0, stream>>>((const float*)d_out, 2, 1, ln2_g, ln2_b, ln2b);
    gemm_lds<128, 128, 2, 0><<<dim3(24, 64), 256, 0, stream>>>(
        ln2b, w1T, b1, nullptr, nullptr, h1, 8192, 3072, 768);
    gemm_lds<128, 128, 3, 1><<<dim3(6, 64), 256, 0, stream>>>(
        h1, w2T, b2, x, nullptr, out, 8192, 768, 3072);
  }
}

// Round 6
// 437.025 us; speedup vs baseline: 1.0341x; 1.0328x over previous
//
#include <hip/hip_runtime.h>
#include <cstdint>
#include <cstddef>

// ---------- types & helpers ----------
typedef __attribute__((ext_vector_type(8))) short bfr8;   // 8 bf16 = 4 VGPRs
typedef __attribute__((ext_vector_type(4))) float acc4;   // MFMA accumulator

__device__ __forceinline__ float bf2f(short s) {
  return __uint_as_float(((unsigned)(unsigned short)s) << 16);
}
__device__ __forceinline__ short f2bf(float f) {
  unsigned u = __float_as_uint(f);
  u += 0x7fffu + ((u >> 16) & 1u);   // round-to-nearest-even
  return (short)(u >> 16);
}
// fast tanh-approx GELU
__device__ __forceinline__ float gelu_f(float x) {
  float z = 0.7978845608028654f * (x + 0.044715f * x * x * x);
  z = fminf(fmaxf(z, -12.f), 12.f);
  float e = __expf(2.f * z);
  float th = (e - 1.f) / (e + 1.f);
  return 0.5f * x * (1.f + th);
}
// async global->LDS, 16B per lane; lds dest = wave-uniform base + lane*16
__device__ __forceinline__ void load_lds16(const short* g, short* l) {
  __builtin_amdgcn_global_load_lds(
      (const __attribute__((address_space(1))) void*)g,
      (__attribute__((address_space(3))) void*)l, 16, 0, 0);
}

// Problem constants
#define BB 2
#define SS 4096
#define DD 768
#define HH 12
#define BLKSZ 64
#define NBLK 64
#define HDIM 64

// ---------- merged weight prep: 6 transposes (fp32[K][N] -> bf16[N][K]) + bias concat ----------
__global__ __launch_bounds__(256) void prep_weights(
    const float* __restrict__ wq, const float* __restrict__ wk,
    const float* __restrict__ wv, const float* __restrict__ wo,
    const float* __restrict__ w1, const float* __restrict__ w2,
    const float* __restrict__ bq, const float* __restrict__ bk,
    const float* __restrict__ bv, float* __restrict__ bqkv,
    short* __restrict__ wqT, short* __restrict__ wkT, short* __restrict__ wvT,
    short* __restrict__ woT, short* __restrict__ w1T, short* __restrict__ w2T) {
  int id = blockIdx.x;
  if (id >= 6912) {  // bias concat, 9 blocks x 256 = 2304
    int t = (id - 6912) * 256 + threadIdx.x;
    bqkv[t] = (t < 768) ? bq[t] : (t < 1536) ? bk[t - 768] : bv[t - 1536];
    return;
  }
  const float* src; short* dst; int K, N, n0, k0;
  if (id < 2304) {
    int seg = id / 576, local = id % 576;
    K = 768; N = 768;
    n0 = (local % 24) * 32; k0 = (local / 24) * 32;
    src = seg == 0 ? wq : seg == 1 ? wk : seg == 2 ? wv : wo;
    dst = seg == 0 ? wqT : seg == 1 ? wkT : seg == 2 ? wvT : woT;
  } else if (id < 4608) {
    int local = id - 2304;
    K = 768; N = 3072;
    n0 = (local % 96) * 32; k0 = (local / 96) * 32;
    src = w1; dst = w1T;
  } else {
    int local = id - 4608;
    K = 3072; N = 768;
    n0 = (local % 24) * 32; k0 = (local / 24) * 32;
    src = w2; dst = w2T;
  }
  __shared__ float tile[32][33];
  int tx = threadIdx.x & 31, ty = threadIdx.x >> 5;  // ty in 0..7
#pragma unroll
  for (int i = 0; i < 4; i++) {
    int kk = ty + i * 8;
    tile[kk][tx] = src[(size_t)(k0 + kk) * N + n0 + tx];
  }
  __syncthreads();
#pragma unroll
  for (int i = 0; i < 4; i++) {
    int nn = ty + i * 8;
    dst[(size_t)(n0 + nn) * K + k0 + tx] = f2bf(tile[tx][nn]);
  }
}

// ---------- transpose bf16 [B][S][D] -> [B][D][S] ----------
__global__ __launch_bounds__(256) void transpose_bf16(
    const short* __restrict__ src, short* __restrict__ dst) {
  __shared__ short tile[32][33];
  int b = blockIdx.z;
  int s0 = blockIdx.x * 32, d0 = blockIdx.y * 32;
  int tx = threadIdx.x & 31, ty = threadIdx.x >> 5;  // 0..7
#pragma unroll
  for (int i = 0; i < 4; i++) {
    int ss = ty + i * 8;
    tile[ss][tx] = src[((size_t)b * SS + s0 + ss) * DD + d0 + tx];
  }
  __syncthreads();
#pragma unroll
  for (int i = 0; i < 4; i++) {
    int dd = ty + i * 8;
    dst[((size_t)b * DD + d0 + dd) * SS + s0 + tx] = tile[tx][dd];
  }
}

// ---------- LayerNorm: strided fp32 in -> contiguous bf16 out [rows][768] ----------
__global__ __launch_bounds__(256) void ln_kernel(
    const float* __restrict__ in, int stride, int off,
    const float* __restrict__ gam, const float* __restrict__ bet,
    short* __restrict__ out) {
  int row = blockIdx.x;
  int t = threadIdx.x;
  const float* base = in + (size_t)row * 768 * stride + off;
  float vals[3], s = 0.f, s2 = 0.f;
#pragma unroll
  for (int i = 0; i < 3; i++) {
    int d = t + 256 * i;
    float v = base[(size_t)d * stride];
    vals[i] = v; s += v; s2 += v * v;
  }
#pragma unroll
  for (int o = 32; o; o >>= 1) { s += __shfl_down(s, o); s2 += __shfl_down(s2, o); }
  __shared__ float red[8];
  int lane = t & 63, w = t >> 6;
  if (lane == 0) { red[w] = s; red[4 + w] = s2; }
  __syncthreads();
  s = red[0] + red[1] + red[2] + red[3];
  s2 = red[4] + red[5] + red[6] + red[7];
  float mean = s * (1.f / 768.f);
  float var = s2 * (1.f / 768.f) - mean * mean;
  float rstd = rsqrtf(var + 1e-6f);
#pragma unroll
  for (int i = 0; i < 3; i++) {
    int d = t + 256 * i;
    out[(size_t)row * 768 + d] = f2bf((vals[i] - mean) * rstd * gam[d] + bet[d]);
  }
}

// ---------- 2-phase bf16 MFMA GEMM (R3-proven config: best measured) ----------
// Tile BMxBN (128x128), 4 waves 2x2. XCD-chunked remap (T1) + counted-vmcnt
// double-buffer (T4) + XOR-swizzled LDS (T2).  8-phase/256-tile variant was
// tried in R4/R5 and REGRESSED: 288/384-block grids at 1 block/CU quantize to
// 2 full rounds (1.78x/1.33x inflation) — tile mis-sized for these shapes.
template <int BM, int BN, int EPI, int SWZ>
__global__ __launch_bounds__(256) void gemm_lds(
    const short* __restrict__ A, const short* __restrict__ BT,
    const float* __restrict__ bias, const float* __restrict__ xres,
    const float* __restrict__ aux, void* __restrict__ outp, int M, int N, int K) {
  __shared__ alignas(16) short As[2][BM * 64];
  __shared__ alignas(16) short Bs[2][BN * 64];
  constexpr int TI = BM / 32;
  constexpr int TJ = BN / 32;
  static_assert(TI + TJ == 8, "vmcnt(8) immediate assumes 8 loads/tile/wave");
  int orig = blockIdx.x + gridDim.x * blockIdx.y;
  int gx = gridDim.x;
  int mchunk = gridDim.y >> 3;
  int xcd = orig & 7, l = orig >> 3;
  int mb, nb;
  if (SWZ == 0) { nb = l / mchunk; mb = xcd * mchunk + (l % mchunk); }
  else          { nb = l % gx;     mb = xcd * mchunk + (l / gx); }
  int m0 = mb * BM, n0 = nb * BN;
  int t = threadIdx.x;
  int lane = t & 63, wave = t >> 6;
  int wm = (wave >> 1) * (BM / 2), wn = (wave & 1) * (BN / 2);
  int quad = lane >> 4, lc = lane & 15;
  acc4 acc[TI][TJ];
#pragma unroll
  for (int i = 0; i < TI; i++)
#pragma unroll
    for (int j = 0; j < TJ; j++) acc[i][j] = (acc4){0.f, 0.f, 0.f, 0.f};

  int lrow = lane >> 3;
  int scol = ((lane & 7) ^ lrow) * 8;
  const short* Ag = A + (size_t)(m0 + wave * (BM / 4) + lrow) * K + scol;
  const short* Bg = BT + (size_t)(n0 + wave * (BN / 4) + lrow) * K + scol;
  int aoff = wave * (BM * 16);
  int boff = wave * (BN * 16);
  int rsw = (lc & 7) << 4;

  const int nk = K >> 6;
#pragma unroll
  for (int j = 0; j < TI; j++)
    load_lds16(Ag + (size_t)(j * 8) * K, &As[0][aoff + j * 512]);
#pragma unroll
  for (int j = 0; j < TJ; j++)
    load_lds16(Bg + (size_t)(j * 8) * K, &Bs[0][boff + j * 512]);
  if (nk > 1) {
#pragma unroll
    for (int j = 0; j < TI; j++)
      load_lds16(Ag + 64 + (size_t)(j * 8) * K, &As[1][aoff + j * 512]);
#pragma unroll
    for (int j = 0; j < TJ; j++)
      load_lds16(Bg + 64 + (size_t)(j * 8) * K, &Bs[1][boff + j * 512]);
  }

  for (int it = 0; it < nk; ++it) {
    int cur = it & 1;
    if (it + 1 < nk) asm volatile("s_waitcnt vmcnt(8)" ::: "memory");
    else             asm volatile("s_waitcnt vmcnt(0)" ::: "memory");
    __builtin_amdgcn_s_barrier();
    __builtin_amdgcn_sched_barrier(0);
    const char* Ab = (const char*)&As[cur][0];
    const char* Bb = (const char*)&Bs[cur][0];
#pragma unroll
    for (int kk = 0; kk < 2; kk++) {
      int rboff = ((kk << 6) | (quad << 4)) ^ rsw;
      bfr8 afr[TI], bfr[TJ];
#pragma unroll
      for (int i = 0; i < TI; i++)
        afr[i] = *(const bfr8*)(Ab + (wm + i * 16 + lc) * 128 + rboff);
#pragma unroll
      for (int j = 0; j < TJ; j++)
        bfr[j] = *(const bfr8*)(Bb + (wn + j * 16 + lc) * 128 + rboff);
#pragma unroll
      for (int i = 0; i < TI; i++)
#pragma unroll
        for (int j = 0; j < TJ; j++)
          acc[i][j] = __builtin_amdgcn_mfma_f32_16x16x32_bf16(afr[i], bfr[j], acc[i][j], 0, 0, 0);
    }
    if (it < nk - 2) {
      __builtin_amdgcn_sched_barrier(0);
      __builtin_amdgcn_s_barrier();
      __builtin_amdgcn_sched_barrier(0);
      int k0 = (it + 2) << 6;
#pragma unroll
      for (int j = 0; j < TI; j++)
        load_lds16(Ag + k0 + (size_t)(j * 8) * K, &As[cur][aoff + j * 512]);
#pragma unroll
      for (int j = 0; j < TJ; j++)
        load_lds16(Bg + k0 + (size_t)(j * 8) * K, &Bs[cur][boff + j * 512]);
    }
  }
  // epilogue: C/D layout col=lane&15, row=(lane>>4)*4+reg
#pragma unroll
  for (int i = 0; i < TI; i++) {
#pragma unroll
    for (int j = 0; j < TJ; j++) {
      int col = n0 + wn + j * 16 + lc;
      float bv = bias[col];
#pragma unroll
      for (int r = 0; r < 4; r++) {
        int row = m0 + wm + i * 16 + quad * 4 + r;
        float v = acc[i][j][r] + bv;
        size_t idx = (size_t)row * N + col;
        if (EPI == 1) {
          v += xres[idx * 2];
          ((float*)outp)[idx * 2 + 1] = v;
        } else if (EPI == 2) {
          ((short*)outp)[idx] = f2bf(gelu_f(v));
        } else if (EPI == 3) {
          v += xres[idx * 2 + 1];
          ((float*)outp)[idx * 2] = v;
        } else if (EPI == 4) {
          int bufidx = col / 768;
          int colm = col - bufidx * 768;
          ((short*)outp)[(size_t)bufidx * 6291456 + (size_t)row * 768 + colm] = f2bf(v);
        } else if (EPI == 5) {
          v += xres[idx * 2];
          ((float*)outp)[idx] = v;
        } else {  // EPI 6
          v += xres[idx * 2 + 1];
          float2 pr; pr.x = v; pr.y = aux[idx];
          ((float2*)outp)[idx] = pr;
        }
      }
    }
  }
}

// ---------- MFMA attention core: T14 async-stage + LDS double-buffer ----------
// Per K-chunk: issue NEXT chunk's K/V global loads into registers BEFORE the
// compute (they fly under QK+softmax+PV, ~1500+ cyc >> L2/HBM latency), write
// them to the OTHER LDS buffer after PV, ONE barrier per chunk.
// Safety (one-barrier dbuf): within an inter-barrier window, reads hit
// buf[cur], prefetch writes hit buf[cur^1] (disjoint); __syncthreads drains
// vm+lgkm so writes are visible across the barrier; buf[cur] is restaged only
// in the NEXT window, after all its readers passed this barrier.
__device__ __forceinline__ void attn_core(
    const short* __restrict__ qrow0, const short* __restrict__ kbase,
    const short* __restrict__ vt_h, const int* kblist, int nch, int t,
    short (*QPs)[72], short (*Ksb)[64][72], short (*Vtsb)[64][72],
    float* m, float* l, acc4* O) {
  int lane = t & 63, w = t >> 6, quad = lane >> 4, lc = lane & 15;
  const int ra = t >> 3;            // 0..31
  const int rb = ra + 32;           // 32..63
  const int ca = (t & 7) * 8;       // element col of this thread's 8-elem chunk
  // stage Q and chunk 0's K/V
  *(bfr8*)&QPs[ra][ca] = *(const bfr8*)&qrow0[(size_t)ra * DD + ca];
  *(bfr8*)&QPs[rb][ca] = *(const bfr8*)&qrow0[(size_t)rb * DD + ca];
  {
    int kb = kblist[0];
    *(bfr8*)&Ksb[0][ra][ca] = *(const bfr8*)&kbase[((size_t)kb * 64 + ra) * DD + ca];
    *(bfr8*)&Ksb[0][rb][ca] = *(const bfr8*)&kbase[((size_t)kb * 64 + rb) * DD + ca];
    *(bfr8*)&Vtsb[0][ra][ca] = *(const bfr8*)&vt_h[(size_t)ra * SS + kb * 64 + ca];
    *(bfr8*)&Vtsb[0][rb][ca] = *(const bfr8*)&vt_h[(size_t)rb * SS + kb * 64 + ca];
  }
  __syncthreads();
  bfr8 aq0 = *(const bfr8*)&QPs[w * 16 + lc][quad * 8];
  bfr8 aq1 = *(const bfr8*)&QPs[w * 16 + lc][32 + quad * 8];
#pragma unroll
  for (int r = 0; r < 4; r++) { m[r] = -1e30f; l[r] = 0.f; }
#pragma unroll
  for (int dt = 0; dt < 4; dt++) O[dt] = (acc4){0.f, 0.f, 0.f, 0.f};

  for (int ch = 0; ch < nch; ch++) {
    int cur = ch & 1;
    short (*Ks)[72] = Ksb[cur];
    short (*Vts)[72] = Vtsb[cur];
    // T14 issue-early: next chunk's loads fly under this chunk's compute
    bfr8 kA, kB, vA, vB;
    const bool pf = (ch + 1 < nch);
    if (pf) {
      int kb = kblist[ch + 1];
      kA = *(const bfr8*)&kbase[((size_t)kb * 64 + ra) * DD + ca];
      kB = *(const bfr8*)&kbase[((size_t)kb * 64 + rb) * DD + ca];
      vA = *(const bfr8*)&vt_h[(size_t)ra * SS + kb * 64 + ca];
      vB = *(const bfr8*)&vt_h[(size_t)rb * SS + kb * 64 + ca];
    }
    // QK^T
    acc4 sacc[4];
#pragma unroll
    for (int nt = 0; nt < 4; nt++) {
      bfr8 bk0 = *(const bfr8*)&Ks[nt * 16 + lc][quad * 8];
      bfr8 bk1 = *(const bfr8*)&Ks[nt * 16 + lc][32 + quad * 8];
      acc4 z = (acc4){0.f, 0.f, 0.f, 0.f};
      z = __builtin_amdgcn_mfma_f32_16x16x32_bf16(aq0, bk0, z, 0, 0, 0);
      z = __builtin_amdgcn_mfma_f32_16x16x32_bf16(aq1, bk1, z, 0, 0, 0);
      sacc[nt] = z;
    }
    // online softmax (wave-parallel)
#pragma unroll
    for (int r = 0; r < 4; r++) {
      float sv[4];
#pragma unroll
      for (int nt = 0; nt < 4; nt++) sv[nt] = sacc[nt][r] * 0.125f;
      float cm = fmaxf(fmaxf(sv[0], sv[1]), fmaxf(sv[2], sv[3]));
      cm = fmaxf(cm, __shfl_xor(cm, 1));
      cm = fmaxf(cm, __shfl_xor(cm, 2));
      cm = fmaxf(cm, __shfl_xor(cm, 4));
      cm = fmaxf(cm, __shfl_xor(cm, 8));
      float mn = fmaxf(m[r], cm);
      float al = __expf(m[r] - mn);
      m[r] = mn;
      float ls = 0.f;
#pragma unroll
      for (int nt = 0; nt < 4; nt++) {
        float p = __expf(sv[nt] - mn);
        ls += p;
        QPs[w * 16 + quad * 4 + r][nt * 16 + lc] = f2bf(p);
      }
      ls += __shfl_xor(ls, 1);
      ls += __shfl_xor(ls, 2);
      ls += __shfl_xor(ls, 4);
      ls += __shfl_xor(ls, 8);
      l[r] = l[r] * al + ls;
#pragma unroll
      for (int dt = 0; dt < 4; dt++) O[dt][r] *= al;
    }
    // PV
    bfr8 ap0 = *(const bfr8*)&QPs[w * 16 + lc][quad * 8];
    bfr8 ap1 = *(const bfr8*)&QPs[w * 16 + lc][32 + quad * 8];
#pragma unroll
    for (int dt = 0; dt < 4; dt++) {
      bfr8 bv0 = *(const bfr8*)&Vts[dt * 16 + lc][quad * 8];
      bfr8 bv1 = *(const bfr8*)&Vts[dt * 16 + lc][32 + quad * 8];
      O[dt] = __builtin_amdgcn_mfma_f32_16x16x32_bf16(ap0, bv0, O[dt], 0, 0, 0);
      O[dt] = __builtin_amdgcn_mfma_f32_16x16x32_bf16(ap1, bv1, O[dt], 0, 0, 0);
    }
    // T14 write-late: land prefetch into the other buffer, then ONE barrier
    if (pf) {
      int nxt = cur ^ 1;
      *(bfr8*)&Ksb[nxt][ra][ca] = kA;
      *(bfr8*)&Ksb[nxt][rb][ca] = kB;
      *(bfr8*)&Vtsb[nxt][ra][ca] = vA;
      *(bfr8*)&Vtsb[nxt][rb][ca] = vB;
    }
    __syncthreads();
  }
}

// middle query blocks: n = 1..62; keys = {0, 63, n-1, n, n+1, r0, r1, r2}
__global__ __launch_bounds__(256) void attn_mid_mfma(
    const short* __restrict__ qbuf, const short* __restrict__ kbuf,
    const short* __restrict__ vtbuf, const int* __restrict__ rand_attn,
    short* __restrict__ ao) {
  int n = 1 + blockIdx.x;  // 1..62
  int h = blockIdx.y, b = blockIdx.z;
  int t = threadIdx.x, lane = t & 63, w = t >> 6, quad = lane >> 4, lc = lane & 15;
  int hoff = h * HDIM;
  size_t btok = (size_t)b * SS;
  __shared__ alignas(16) short QPs[64][72];
  __shared__ alignas(16) short Ksb[2][64][72], Vtsb[2][64][72];
  int kblist[8];
  kblist[0] = 0; kblist[1] = NBLK - 1;
  kblist[2] = n - 1; kblist[3] = n; kblist[4] = n + 1;
#pragma unroll
  for (int r = 0; r < 3; r++)
    kblist[5 + r] = rand_attn[((size_t)h * 62 + (n - 1)) * 3 + r];
  float m[4], l[4]; acc4 O[4];
  attn_core(qbuf + (btok + (size_t)n * 64) * DD + hoff,
            kbuf + btok * DD + hoff,
            vtbuf + ((size_t)b * DD + hoff) * SS,
            kblist, 8, t, QPs, Ksb, Vtsb, m, l, O);
#pragma unroll
  for (int r = 0; r < 4; r++) {
    float inv = 1.f / l[r];
    size_t tok = btok + (size_t)n * 64 + w * 16 + quad * 4 + r;
    short* op = ao + tok * DD + hoff;
#pragma unroll
    for (int dt = 0; dt < 4; dt++) op[dt * 16 + lc] = f2bf(O[dt][r] * inv);
  }
}

// global query blocks (0 and 63), split-K over 8 splits of 8 key-blocks each
__global__ __launch_bounds__(256) void attn_glb_mfma(
    const short* __restrict__ qbuf, const short* __restrict__ kbuf,
    const short* __restrict__ vtbuf, float* __restrict__ part) {
  int g = blockIdx.x & 1, s = blockIdx.x >> 1;  // grid.x = 16
  int h = blockIdx.y, b = blockIdx.z;
  int t = threadIdx.x, lane = t & 63, w = t >> 6, quad = lane >> 4, lc = lane & 15;
  int hoff = h * HDIM;
  size_t btok = (size_t)b * SS;
  int qblk = g ? (NBLK - 1) : 0;
  __shared__ alignas(16) short QPs[64][72];
  __shared__ alignas(16) short Ksb[2][64][72], Vtsb[2][64][72];
  int kblist[8];
#pragma unroll
  for (int c = 0; c < 8; c++) kblist[c] = s * 8 + c;
  float m[4], l[4]; acc4 O[4];
  attn_core(qbuf + (btok + (size_t)qblk * 64) * DD + hoff,
            kbuf + btok * DD + hoff,
            vtbuf + ((size_t)b * DD + hoff) * SS,
            kblist, 8, t, QPs, Ksb, Vtsb, m, l, O);
  float* pp = part + ((((size_t)b * HH + h) * 2 + g) * 8 + s) * 4224;
#pragma unroll
  for (int r = 0; r < 4; r++) {
    int row = w * 16 + quad * 4 + r;
#pragma unroll
    for (int dt = 0; dt < 4; dt++) pp[row * 64 + dt * 16 + lc] = O[dt][r];  // unnormalized
    if (lc == 0) {
      pp[4096 + row] = m[r];
      pp[4160 + row] = l[r];
    }
  }
}

__global__ __launch_bounds__(256) void attn_combine(
    const float* __restrict__ part, short* __restrict__ ao) {
  int g = blockIdx.x, h = blockIdx.y, b = blockIdx.z;
  int t = threadIdx.x, qrow = t >> 2, sub = t & 3;
  const float* base = part + (((size_t)b * HH + h) * 2 + g) * 8 * 4224;
  float mm[8], ll[8], M = -1e30f;
#pragma unroll
  for (int s = 0; s < 8; s++) {
    mm[s] = base[s * 4224 + 4096 + qrow];
    ll[s] = base[s * 4224 + 4160 + qrow];
    M = fmaxf(M, mm[s]);
  }
  float L = 0.f, O[16];
#pragma unroll
  for (int d = 0; d < 16; d++) O[d] = 0.f;
#pragma unroll
  for (int s = 0; s < 8; s++) {
    float w = __expf(mm[s] - M);
    L += w * ll[s];
    const float* Op = base + s * 4224 + qrow * 64 + sub * 16;
#pragma unroll
    for (int d = 0; d < 16; d++) O[d] += w * Op[d];
  }
  float inv = 1.f / L;
  int qblk = g ? (NBLK - 1) : 0;
  size_t tok = (size_t)b * SS + (size_t)qblk * BLKSZ + qrow;
  short* op = ao + tok * DD + h * HDIM + sub * 16;
#pragma unroll
  for (int d = 0; d < 16; d++) op[d] = f2bf(O[d] * inv);
}

// ---------- launch ----------
extern "C" void kernel_launch(void* const* d_in, const int* in_sizes, int n_in,
                              void* d_out, int out_size, void* d_ws, size_t ws_size,
                              hipStream_t stream) {
  (void)in_sizes; (void)n_in; (void)out_size;
  const float* x     = (const float*)d_in[0];
  const float* ln1_g = (const float*)d_in[1];
  const float* ln1_b = (const float*)d_in[2];
  const float* ln2_g = (const float*)d_in[3];
  const float* ln2_b = (const float*)d_in[4];
  const float* wq = (const float*)d_in[5];
  const float* bq = (const float*)d_in[6];
  const float* wk = (const float*)d_in[7];
  const float* bk = (const float*)d_in[8];
  const float* wv = (const float*)d_in[9];
  const float* bv = (const float*)d_in[10];
  const float* wo = (const float*)d_in[11];
  const float* bo = (const float*)d_in[12];
  const float* w1 = (const float*)d_in[13];
  const float* b1 = (const float*)d_in[14];
  const float* w2 = (const float*)d_in[15];
  const float* b2 = (const float*)d_in[16];
  const int* rand_attn = (const int*)d_in[17];
  float* out = (float*)d_out;

  short* wsb = (short*)d_ws;
  const size_t WD = 589824;    // 768*768
  const size_t WB = 2359296;   // 768*3072
  const size_t ACT = 6291456;  // 8192*768
  short* wqT = wsb;
  short* wkT = wqT + WD;
  short* wvT = wkT + WD;
  short* woT = wvT + WD;
  short* w1T = woT + WD;   // [3072][768]
  short* w2T = w1T + WB;   // [768][3072]
  short* xln = w2T + WB;   // slot A
  short* qb  = xln + ACT;  // slot B
  short* kb  = qb + ACT;   // slot C
  short* vb  = kb + ACT;   // slot D
  short* aob = vb + ACT;   // slot E
  float* partp = (float*)(aob + ACT);
  float* bqkv = partp + 1622016;
  float* y2f  = bqkv + 2304;
  short* vbT = xln;
  short* h1 = xln;
  short* ln2b = aob;

  const size_t NEED = ((size_t)(y2f + ACT) - (size_t)d_ws);
  bool big = ws_size >= NEED;

  // 1) weight transpose+cast + bias concat
  prep_weights<<<6921, 256, 0, stream>>>(wq, wk, wv, wo, w1, w2, bq, bk, bv, bqkv,
                                         wqT, wkT, wvT, woT, w1T, w2T);

  // 2) LN1 on x1 (= x[...,1])
  ln_kernel<<<8192, 256, 0, stream>>>(x, 2, 1, ln1_g, ln1_b, xln);

  // 3) fused QKV projection  (2-phase, K=768 -> m-fastest swizzle)
  gemm_lds<128, 128, 4, 0><<<dim3(18, 64), 256, 0, stream>>>(
      xln, wqT, bqkv, nullptr, nullptr, qb, 8192, 2304, 768);

  // 3b) V -> V^T [B][D][S]
  transpose_bf16<<<dim3(128, 24, 2), 256, 0, stream>>>(vb, vbT);

  // 4) attention (MFMA, T14 dbuf)
  attn_mid_mfma<<<dim3(62, 12, 2), 256, 0, stream>>>(qb, kb, vbT, rand_attn, aob);
  attn_glb_mfma<<<dim3(16, 12, 2), 256, 0, stream>>>(qb, kb, vbT, partp);
  attn_combine<<<dim3(2, 12, 2), 256, 0, stream>>>(partp, aob);

  if (big) {
    // 5) out-proj + residual(x2) -> y2f contiguous fp32  (2-phase, K=768)
    gemm_lds<128, 128, 5, 0><<<dim3(6, 64), 256, 0, stream>>>(
        aob, woT, bo, x, nullptr, y2f, 8192, 768, 768);
    // 6) LN2 on y2f (contiguous)
    ln_kernel<<<8192, 256, 0, stream>>>(y2f, 1, 0, ln2_g, ln2_b, ln2b);
    // 7) MLP  (both 2-phase; MLP2 K=3072 -> n-fastest)
    gemm_lds<128, 128, 2, 0><<<dim3(24, 64), 256, 0, stream>>>(
        ln2b, w1T, b1, nullptr, nullptr, h1, 8192, 3072, 768);
    gemm_lds<128, 128, 6, 1><<<dim3(6, 64), 256, 0, stream>>>(
        h1, w2T, b2, x, y2f, out, 8192, 768, 3072);
  } else {
    // fallback: interleaved path (all 2-phase)
    gemm_lds<128, 128, 1, 0><<<dim3(6, 64), 256, 0, stream>>>(
        aob, woT, bo, x, nullptr, out, 8192, 768, 768);
    ln_kernel<<<8192, 256, 0, stream>>>((const float*)d_out, 2, 1, ln2_g, ln2_b, ln2b);
    gemm_lds<128, 128, 2, 0><<<dim3(24, 64), 256, 0, stream>>>(
        ln2b, w1T, b1, nullptr, nullptr, h1, 8192, 3072, 768);
    gemm_lds<128, 128, 3, 1><<<dim3(6, 64), 256, 0, stream>>>(
        h1, w2T, b2, x, nullptr, out, 8192, 768, 3072);
  }
}

// Round 8
// 397.790 us; speedup vs baseline: 1.1361x; 1.0986x over previous
//
#include <hip/hip_runtime.h>
#include <cstdint>
#include <cstddef>

// ---------- types & helpers ----------
typedef __attribute__((ext_vector_type(8))) short bfr8;   // 8 bf16 = 4 VGPRs
typedef __attribute__((ext_vector_type(4))) float acc4;   // MFMA accumulator

__device__ __forceinline__ float bf2f(short s) {
  return __uint_as_float(((unsigned)(unsigned short)s) << 16);
}
__device__ __forceinline__ short f2bf(float f) {
  unsigned u = __float_as_uint(f);
  u += 0x7fffu + ((u >> 16) & 1u);   // round-to-nearest-even
  return (short)(u >> 16);
}
// fast tanh-approx GELU
__device__ __forceinline__ float gelu_f(float x) {
  float z = 0.7978845608028654f * (x + 0.044715f * x * x * x);
  z = fminf(fmaxf(z, -12.f), 12.f);
  float e = __expf(2.f * z);
  float th = (e - 1.f) / (e + 1.f);
  return 0.5f * x * (1.f + th);
}
// async global->LDS, 16B per lane; lds dest = wave-uniform base + lane*16
__device__ __forceinline__ void load_lds16(const short* g, short* l) {
  __builtin_amdgcn_global_load_lds(
      (const __attribute__((address_space(1))) void*)g,
      (__attribute__((address_space(3))) void*)l, 16, 0, 0);
}

// Problem constants
#define BB 2
#define SS 4096
#define DD 768
#define HH 12
#define BLKSZ 64
#define NBLK 64
#define HDIM 64

// ---------- merged weight prep: 6 transposes (fp32[K][N] -> bf16[N][K]) + bias concat ----------
__global__ __launch_bounds__(256) void prep_weights(
    const float* __restrict__ wq, const float* __restrict__ wk,
    const float* __restrict__ wv, const float* __restrict__ wo,
    const float* __restrict__ w1, const float* __restrict__ w2,
    const float* __restrict__ bq, const float* __restrict__ bk,
    const float* __restrict__ bv, float* __restrict__ bqkv,
    short* __restrict__ wqT, short* __restrict__ wkT, short* __restrict__ wvT,
    short* __restrict__ woT, short* __restrict__ w1T, short* __restrict__ w2T) {
  int id = blockIdx.x;
  if (id >= 6912) {  // bias concat, 9 blocks x 256 = 2304
    int t = (id - 6912) * 256 + threadIdx.x;
    bqkv[t] = (t < 768) ? bq[t] : (t < 1536) ? bk[t - 768] : bv[t - 1536];
    return;
  }
  const float* src; short* dst; int K, N, n0, k0;
  if (id < 2304) {
    int seg = id / 576, local = id % 576;
    K = 768; N = 768;
    n0 = (local % 24) * 32; k0 = (local / 24) * 32;
    src = seg == 0 ? wq : seg == 1 ? wk : seg == 2 ? wv : wo;
    dst = seg == 0 ? wqT : seg == 1 ? wkT : seg == 2 ? wvT : woT;
  } else if (id < 4608) {
    int local = id - 2304;
    K = 768; N = 3072;
    n0 = (local % 96) * 32; k0 = (local / 96) * 32;
    src = w1; dst = w1T;
  } else {
    int local = id - 4608;
    K = 3072; N = 768;
    n0 = (local % 24) * 32; k0 = (local / 24) * 32;
    src = w2; dst = w2T;
  }
  __shared__ float tile[32][33];
  int tx = threadIdx.x & 31, ty = threadIdx.x >> 5;  // ty in 0..7
#pragma unroll
  for (int i = 0; i < 4; i++) {
    int kk = ty + i * 8;
    tile[kk][tx] = src[(size_t)(k0 + kk) * N + n0 + tx];
  }
  __syncthreads();
#pragma unroll
  for (int i = 0; i < 4; i++) {
    int nn = ty + i * 8;
    dst[(size_t)(n0 + nn) * K + k0 + tx] = f2bf(tile[tx][nn]);
  }
}

// ---------- LayerNorm: strided fp32 in -> contiguous bf16 out [rows][768] ----------
__global__ __launch_bounds__(256) void ln_kernel(
    const float* __restrict__ in, int stride, int off,
    const float* __restrict__ gam, const float* __restrict__ bet,
    short* __restrict__ out) {
  int row = blockIdx.x;
  int t = threadIdx.x;
  float vals[3], s = 0.f, s2 = 0.f;
  if (stride == 2) {
    // vectorized: float2 per element, pick lane 'off' (same cachelines, half the loads)
    const float2* base2 = (const float2*)(in + (size_t)row * 768 * 2);
#pragma unroll
    for (int i = 0; i < 3; i++) {
      int d = t + 256 * i;
      float2 p = base2[d];
      float v = off ? p.y : p.x;
      vals[i] = v; s += v; s2 += v * v;
    }
  } else {
    const float* base = in + (size_t)row * 768 + off;
#pragma unroll
    for (int i = 0; i < 3; i++) {
      int d = t + 256 * i;
      float v = base[d];
      vals[i] = v; s += v; s2 += v * v;
    }
  }
#pragma unroll
  for (int o = 32; o; o >>= 1) { s += __shfl_down(s, o); s2 += __shfl_down(s2, o); }
  __shared__ float red[8];
  int lane = t & 63, w = t >> 6;
  if (lane == 0) { red[w] = s; red[4 + w] = s2; }
  __syncthreads();
  s = red[0] + red[1] + red[2] + red[3];
  s2 = red[4] + red[5] + red[6] + red[7];
  float mean = s * (1.f / 768.f);
  float var = s2 * (1.f / 768.f) - mean * mean;
  float rstd = rsqrtf(var + 1e-6f);
#pragma unroll
  for (int i = 0; i < 3; i++) {
    int d = t + 256 * i;
    out[(size_t)row * 768 + d] = f2bf((vals[i] - mean) * rstd * gam[d] + bet[d]);
  }
}

// ---------- 2-phase bf16 MFMA GEMM (R3-proven config: best measured) ----------
// Tile BMxBN (128x128), 4 waves 2x2. XCD-chunked remap (T1) + counted-vmcnt
// double-buffer (T4) + XOR-swizzled LDS (T2).  8-phase/256-tile variant was
// tried in R4/R5 and REGRESSED (grid quantization at these shapes).
// EPI 4 extension: V-tiles (n0>=1536) transpose the C-tile through the dead
// LDS staging buffer and write V^T ([B][D][S]) directly to aux — fuses the
// old transpose_bf16 kernel and V's HBM round-trip into the QKV GEMM.
template <int BM, int BN, int EPI, int SWZ>
__global__ __launch_bounds__(256) void gemm_lds(
    const short* __restrict__ A, const short* __restrict__ BT,
    const float* __restrict__ bias, const float* __restrict__ xres,
    const float* __restrict__ aux, void* __restrict__ outp, int M, int N, int K) {
  __shared__ alignas(16) short smem[2 * (BM + BN) * 64];  // As dbuf | Bs dbuf
  short* Asp = smem;                    // [2][BM*64]
  short* Bsp = smem + 2 * BM * 64;      // [2][BN*64]
  constexpr int TI = BM / 32;
  constexpr int TJ = BN / 32;
  static_assert(TI + TJ == 8, "vmcnt(8) immediate assumes 8 loads/tile/wave");
  int orig = blockIdx.x + gridDim.x * blockIdx.y;
  int gx = gridDim.x;
  int mchunk = gridDim.y >> 3;
  int xcd = orig & 7, l = orig >> 3;
  int mb, nb;
  if (SWZ == 0) { nb = l / mchunk; mb = xcd * mchunk + (l % mchunk); }
  else          { nb = l % gx;     mb = xcd * mchunk + (l / gx); }
  int m0 = mb * BM, n0 = nb * BN;
  int t = threadIdx.x;
  int lane = t & 63, wave = t >> 6;
  int wm = (wave >> 1) * (BM / 2), wn = (wave & 1) * (BN / 2);
  int quad = lane >> 4, lc = lane & 15;
  acc4 acc[TI][TJ];
#pragma unroll
  for (int i = 0; i < TI; i++)
#pragma unroll
    for (int j = 0; j < TJ; j++) acc[i][j] = (acc4){0.f, 0.f, 0.f, 0.f};

  int lrow = lane >> 3;
  int scol = ((lane & 7) ^ lrow) * 8;
  const short* Ag = A + (size_t)(m0 + wave * (BM / 4) + lrow) * K + scol;
  const short* Bg = BT + (size_t)(n0 + wave * (BN / 4) + lrow) * K + scol;
  int aoff = wave * (BM * 16);
  int boff = wave * (BN * 16);
  int rsw = (lc & 7) << 4;

  const int nk = K >> 6;
#pragma unroll
  for (int j = 0; j < TI; j++)
    load_lds16(Ag + (size_t)(j * 8) * K, Asp + aoff + j * 512);
#pragma unroll
  for (int j = 0; j < TJ; j++)
    load_lds16(Bg + (size_t)(j * 8) * K, Bsp + boff + j * 512);
  if (nk > 1) {
#pragma unroll
    for (int j = 0; j < TI; j++)
      load_lds16(Ag + 64 + (size_t)(j * 8) * K, Asp + BM * 64 + aoff + j * 512);
#pragma unroll
    for (int j = 0; j < TJ; j++)
      load_lds16(Bg + 64 + (size_t)(j * 8) * K, Bsp + BN * 64 + boff + j * 512);
  }

  for (int it = 0; it < nk; ++it) {
    int cur = it & 1;
    if (it + 1 < nk) asm volatile("s_waitcnt vmcnt(8)" ::: "memory");
    else             asm volatile("s_waitcnt vmcnt(0)" ::: "memory");
    __builtin_amdgcn_s_barrier();
    __builtin_amdgcn_sched_barrier(0);
    const char* Ab = (const char*)(Asp + cur * BM * 64);
    const char* Bb = (const char*)(Bsp + cur * BN * 64);
#pragma unroll
    for (int kk = 0; kk < 2; kk++) {
      int rboff = ((kk << 6) | (quad << 4)) ^ rsw;
      bfr8 afr[TI], bfr[TJ];
#pragma unroll
      for (int i = 0; i < TI; i++)
        afr[i] = *(const bfr8*)(Ab + (wm + i * 16 + lc) * 128 + rboff);
#pragma unroll
      for (int j = 0; j < TJ; j++)
        bfr[j] = *(const bfr8*)(Bb + (wn + j * 16 + lc) * 128 + rboff);
#pragma unroll
      for (int i = 0; i < TI; i++)
#pragma unroll
        for (int j = 0; j < TJ; j++)
          acc[i][j] = __builtin_amdgcn_mfma_f32_16x16x32_bf16(afr[i], bfr[j], acc[i][j], 0, 0, 0);
    }
    if (it < nk - 2) {
      __builtin_amdgcn_sched_barrier(0);
      __builtin_amdgcn_s_barrier();
      __builtin_amdgcn_sched_barrier(0);
      int k0 = (it + 2) << 6;
#pragma unroll
      for (int j = 0; j < TI; j++)
        load_lds16(Ag + k0 + (size_t)(j * 8) * K, Asp + cur * BM * 64 + aoff + j * 512);
#pragma unroll
      for (int j = 0; j < TJ; j++)
        load_lds16(Bg + k0 + (size_t)(j * 8) * K, Bsp + cur * BN * 64 + boff + j * 512);
    }
  }

  if (EPI == 4 && n0 >= 1536) {
    // ---- V^T path: transpose C-tile via LDS, write [B][D][S] directly ----
    __syncthreads();               // all K-loop LDS reads complete
    short* ot = smem;              // scratch [128 d][136 s] (pad: 136=17*8)
#pragma unroll
    for (int i = 0; i < TI; i++)
#pragma unroll
      for (int j = 0; j < TJ; j++) {
        int col = wn + j * 16 + lc;
        float bv = bias[n0 + col];
#pragma unroll
        for (int r = 0; r < 4; r++) {
          int row = wm + i * 16 + quad * 4 + r;
          ot[col * 136 + row] = f2bf(acc[i][j][r] + bv);
        }
      }
    __syncthreads();
    short* vt = (short*)const_cast<float*>(aux);   // vbT base [2][768][4096]
    int bq_ = m0 >> 12, s0 = m0 & 4095;
    int d0 = n0 - 1536;
#pragma unroll
    for (int q2 = 0; q2 < 8; q2++) {
      int c = q2 * 256 + t;
      int d = c >> 4, sc = (c & 15) * 8;
      *(bfr8*)&vt[((size_t)bq_ * 768 + d0 + d) * 4096 + s0 + sc] =
          *(const bfr8*)&ot[d * 136 + sc];
    }
    return;
  }

  // epilogue: C/D layout col=lane&15, row=(lane>>4)*4+reg
#pragma unroll
  for (int i = 0; i < TI; i++) {
#pragma unroll
    for (int j = 0; j < TJ; j++) {
      int col = n0 + wn + j * 16 + lc;
      float bv = bias[col];
#pragma unroll
      for (int r = 0; r < 4; r++) {
        int row = m0 + wm + i * 16 + quad * 4 + r;
        float v = acc[i][j][r] + bv;
        size_t idx = (size_t)row * N + col;
        if (EPI == 1) {
          v += xres[idx * 2];
          ((float*)outp)[idx * 2 + 1] = v;
        } else if (EPI == 2) {
          ((short*)outp)[idx] = f2bf(gelu_f(v));
        } else if (EPI == 3) {
          v += xres[idx * 2 + 1];
          ((float*)outp)[idx * 2] = v;
        } else if (EPI == 4) {  // q/k tiles: row-major (col<1536)
          int bufidx = col / 768;
          int colm = col - bufidx * 768;
          ((short*)outp)[(size_t)bufidx * 6291456 + (size_t)row * 768 + colm] = f2bf(v);
        } else if (EPI == 5) {
          v += xres[idx * 2];
          ((float*)outp)[idx] = v;
        } else {  // EPI 6
          v += xres[idx * 2 + 1];
          float2 pr; pr.x = v; pr.y = aux[idx];
          ((float2*)outp)[idx] = pr;
        }
      }
    }
  }
}

// ---------- MFMA attention core (T14 dbuf: issue-early/write-late, 1 barrier/chunk) ----------
__device__ __forceinline__ void attn_core(
    const short* __restrict__ qrow0, const short* __restrict__ kbase,
    const short* __restrict__ vt_h, const int* kblist, int nch, int t,
    short (*QPs)[72], short (*Ksb)[64][72], short (*Vtsb)[64][72],
    float* m, float* l, acc4* O) {
  int lane = t & 63, w = t >> 6, quad = lane >> 4, lc = lane & 15;
  const int ra = t >> 3;            // 0..31
  const int rb = ra + 32;           // 32..63
  const int ca = (t & 7) * 8;       // element col of this thread's 8-elem chunk
  *(bfr8*)&QPs[ra][ca] = *(const bfr8*)&qrow0[(size_t)ra * DD + ca];
  *(bfr8*)&QPs[rb][ca] = *(const bfr8*)&qrow0[(size_t)rb * DD + ca];
  {
    int kb = kblist[0];
    *(bfr8*)&Ksb[0][ra][ca] = *(const bfr8*)&kbase[((size_t)kb * 64 + ra) * DD + ca];
    *(bfr8*)&Ksb[0][rb][ca] = *(const bfr8*)&kbase[((size_t)kb * 64 + rb) * DD + ca];
    *(bfr8*)&Vtsb[0][ra][ca] = *(const bfr8*)&vt_h[(size_t)ra * SS + kb * 64 + ca];
    *(bfr8*)&Vtsb[0][rb][ca] = *(const bfr8*)&vt_h[(size_t)rb * SS + kb * 64 + ca];
  }
  __syncthreads();
  bfr8 aq0 = *(const bfr8*)&QPs[w * 16 + lc][quad * 8];
  bfr8 aq1 = *(const bfr8*)&QPs[w * 16 + lc][32 + quad * 8];
#pragma unroll
  for (int r = 0; r < 4; r++) { m[r] = -1e30f; l[r] = 0.f; }
#pragma unroll
  for (int dt = 0; dt < 4; dt++) O[dt] = (acc4){0.f, 0.f, 0.f, 0.f};

  for (int ch = 0; ch < nch; ch++) {
    int cur = ch & 1;
    short (*Ks)[72] = Ksb[cur];
    short (*Vts)[72] = Vtsb[cur];
    bfr8 kA, kB, vA, vB;
    const bool pf = (ch + 1 < nch);
    if (pf) {
      int kb = kblist[ch + 1];
      kA = *(const bfr8*)&kbase[((size_t)kb * 64 + ra) * DD + ca];
      kB = *(const bfr8*)&kbase[((size_t)kb * 64 + rb) * DD + ca];
      vA = *(const bfr8*)&vt_h[(size_t)ra * SS + kb * 64 + ca];
      vB = *(const bfr8*)&vt_h[(size_t)rb * SS + kb * 64 + ca];
    }
    acc4 sacc[4];
#pragma unroll
    for (int nt = 0; nt < 4; nt++) {
      bfr8 bk0 = *(const bfr8*)&Ks[nt * 16 + lc][quad * 8];
      bfr8 bk1 = *(const bfr8*)&Ks[nt * 16 + lc][32 + quad * 8];
      acc4 z = (acc4){0.f, 0.f, 0.f, 0.f};
      z = __builtin_amdgcn_mfma_f32_16x16x32_bf16(aq0, bk0, z, 0, 0, 0);
      z = __builtin_amdgcn_mfma_f32_16x16x32_bf16(aq1, bk1, z, 0, 0, 0);
      sacc[nt] = z;
    }
#pragma unroll
    for (int r = 0; r < 4; r++) {
      float sv[4];
#pragma unroll
      for (int nt = 0; nt < 4; nt++) sv[nt] = sacc[nt][r] * 0.125f;
      float cm = fmaxf(fmaxf(sv[0], sv[1]), fmaxf(sv[2], sv[3]));
      cm = fmaxf(cm, __shfl_xor(cm, 1));
      cm = fmaxf(cm, __shfl_xor(cm, 2));
      cm = fmaxf(cm, __shfl_xor(cm, 4));
      cm = fmaxf(cm, __shfl_xor(cm, 8));
      float mn = fmaxf(m[r], cm);
      float al = __expf(m[r] - mn);
      m[r] = mn;
      float ls = 0.f;
#pragma unroll
      for (int nt = 0; nt < 4; nt++) {
        float p = __expf(sv[nt] - mn);
        ls += p;
        QPs[w * 16 + quad * 4 + r][nt * 16 + lc] = f2bf(p);
      }
      ls += __shfl_xor(ls, 1);
      ls += __shfl_xor(ls, 2);
      ls += __shfl_xor(ls, 4);
      ls += __shfl_xor(ls, 8);
      l[r] = l[r] * al + ls;
#pragma unroll
      for (int dt = 0; dt < 4; dt++) O[dt][r] *= al;
    }
    bfr8 ap0 = *(const bfr8*)&QPs[w * 16 + lc][quad * 8];
    bfr8 ap1 = *(const bfr8*)&QPs[w * 16 + lc][32 + quad * 8];
#pragma unroll
    for (int dt = 0; dt < 4; dt++) {
      bfr8 bv0 = *(const bfr8*)&Vts[dt * 16 + lc][quad * 8];
      bfr8 bv1 = *(const bfr8*)&Vts[dt * 16 + lc][32 + quad * 8];
      O[dt] = __builtin_amdgcn_mfma_f32_16x16x32_bf16(ap0, bv0, O[dt], 0, 0, 0);
      O[dt] = __builtin_amdgcn_mfma_f32_16x16x32_bf16(ap1, bv1, O[dt], 0, 0, 0);
    }
    if (pf) {
      int nxt = cur ^ 1;
      *(bfr8*)&Ksb[nxt][ra][ca] = kA;
      *(bfr8*)&Ksb[nxt][rb][ca] = kB;
      *(bfr8*)&Vtsb[nxt][ra][ca] = vA;
      *(bfr8*)&Vtsb[nxt][rb][ca] = vB;
    }
    __syncthreads();
  }
}

// ---------- fused attention: mid blocks (x<62) + global split-K blocks (x>=62) ----------
// mid: n = 1+x, keys {0, 63, n-1, n, n+1, r0, r1, r2} -> normalized out to ao.
// glb: e = x-62 in [0,16): g=e&1, s=e>>1; qblk = g?63:0, keys s*8..s*8+7 ->
//      unnormalized partials + (m,l) to part (combined by attn_combine).
__global__ __launch_bounds__(256) void attn_fused(
    const short* __restrict__ qbuf, const short* __restrict__ kbuf,
    const short* __restrict__ vtbuf, const int* __restrict__ rand_attn,
    short* __restrict__ ao, float* __restrict__ part) {
  int x = blockIdx.x;  // 0..77
  int h = blockIdx.y, b = blockIdx.z;
  int t = threadIdx.x, lane = t & 63, w = t >> 6, quad = lane >> 4, lc = lane & 15;
  int hoff = h * HDIM;
  size_t btok = (size_t)b * SS;
  __shared__ alignas(16) short QPs[64][72];
  __shared__ alignas(16) short Ksb[2][64][72], Vtsb[2][64][72];
  const bool mid = (x < 62);
  int kblist[8];
  int qblk;
  if (mid) {
    int n = 1 + x;
    qblk = n;
    kblist[0] = 0; kblist[1] = NBLK - 1;
    kblist[2] = n - 1; kblist[3] = n; kblist[4] = n + 1;
#pragma unroll
    for (int r = 0; r < 3; r++)
      kblist[5 + r] = rand_attn[((size_t)h * 62 + (n - 1)) * 3 + r];
  } else {
    int e = x - 62;
    int g = e & 1, s = e >> 1;
    qblk = g ? (NBLK - 1) : 0;
#pragma unroll
    for (int c = 0; c < 8; c++) kblist[c] = s * 8 + c;
  }
  float m[4], l[4]; acc4 O[4];
  attn_core(qbuf + (btok + (size_t)qblk * 64) * DD + hoff,
            kbuf + btok * DD + hoff,
            vtbuf + ((size_t)b * DD + hoff) * SS,
            kblist, 8, t, QPs, Ksb, Vtsb, m, l, O);
  if (mid) {
#pragma unroll
    for (int r = 0; r < 4; r++) {
      float inv = 1.f / l[r];
      size_t tok = btok + (size_t)qblk * 64 + w * 16 + quad * 4 + r;
      short* op = ao + tok * DD + hoff;
#pragma unroll
      for (int dt = 0; dt < 4; dt++) op[dt * 16 + lc] = f2bf(O[dt][r] * inv);
    }
  } else {
    int e = x - 62;
    int g = e & 1, s = e >> 1;
    float* pp = part + ((((size_t)b * HH + h) * 2 + g) * 8 + s) * 4224;
#pragma unroll
    for (int r = 0; r < 4; r++) {
      int row = w * 16 + quad * 4 + r;
#pragma unroll
      for (int dt = 0; dt < 4; dt++) pp[row * 64 + dt * 16 + lc] = O[dt][r];
      if (lc == 0) {
        pp[4096 + row] = m[r];
        pp[4160 + row] = l[r];
      }
    }
  }
}

__global__ __launch_bounds__(256) void attn_combine(
    const float* __restrict__ part, short* __restrict__ ao) {
  int g = blockIdx.x, h = blockIdx.y, b = blockIdx.z;
  int t = threadIdx.x, qrow = t >> 2, sub = t & 3;
  const float* base = part + (((size_t)b * HH + h) * 2 + g) * 8 * 4224;
  float mm[8], ll[8], M = -1e30f;
#pragma unroll
  for (int s = 0; s < 8; s++) {
    mm[s] = base[s * 4224 + 4096 + qrow];
    ll[s] = base[s * 4224 + 4160 + qrow];
    M = fmaxf(M, mm[s]);
  }
  float L = 0.f, O[16];
#pragma unroll
  for (int d = 0; d < 16; d++) O[d] = 0.f;
#pragma unroll
  for (int s = 0; s < 8; s++) {
    float w = __expf(mm[s] - M);
    L += w * ll[s];
    const float* Op = base + s * 4224 + qrow * 64 + sub * 16;
#pragma unroll
    for (int d = 0; d < 16; d++) O[d] += w * Op[d];
  }
  float inv = 1.f / L;
  int qblk = g ? (NBLK - 1) : 0;
  size_t tok = (size_t)b * SS + (size_t)qblk * BLKSZ + qrow;
  short* op = ao + tok * DD + h * HDIM + sub * 16;
#pragma unroll
  for (int d = 0; d < 16; d++) op[d] = f2bf(O[d] * inv);
}

// ---------- launch ----------
extern "C" void kernel_launch(void* const* d_in, const int* in_sizes, int n_in,
                              void* d_out, int out_size, void* d_ws, size_t ws_size,
                              hipStream_t stream) {
  (void)in_sizes; (void)n_in; (void)out_size;
  const float* x     = (const float*)d_in[0];
  const float* ln1_g = (const float*)d_in[1];
  const float* ln1_b = (const float*)d_in[2];
  const float* ln2_g = (const float*)d_in[3];
  const float* ln2_b = (const float*)d_in[4];
  const float* wq = (const float*)d_in[5];
  const float* bq = (const float*)d_in[6];
  const float* wk = (const float*)d_in[7];
  const float* bk = (const float*)d_in[8];
  const float* wv = (const float*)d_in[9];
  const float* bv = (const float*)d_in[10];
  const float* wo = (const float*)d_in[11];
  const float* bo = (const float*)d_in[12];
  const float* w1 = (const float*)d_in[13];
  const float* b1 = (const float*)d_in[14];
  const float* w2 = (const float*)d_in[15];
  const float* b2 = (const float*)d_in[16];
  const int* rand_attn = (const int*)d_in[17];
  float* out = (float*)d_out;

  short* wsb = (short*)d_ws;
  const size_t WD = 589824;    // 768*768
  const size_t WB = 2359296;   // 768*3072
  const size_t ACT = 6291456;  // 8192*768
  short* wqT = wsb;
  short* wkT = wqT + WD;
  short* wvT = wkT + WD;
  short* woT = wvT + WD;
  short* w1T = woT + WD;   // [3072][768]
  short* w2T = w1T + WB;   // [768][3072]
  short* xln = w2T + WB;   // slot A
  short* qb  = xln + ACT;  // slot B
  short* kb  = qb + ACT;   // slot C
  short* vbT = kb + ACT;   // slot D: V^T [2][768][4096], written by QKV epilogue
  short* aob = vbT + ACT;  // slot E
  float* partp = (float*)(aob + ACT);
  float* bqkv = partp + 1622016;
  float* y2f  = bqkv + 2304;
  short* h1 = xln;         // overlays A..D after attention consumed them
  short* ln2b = aob;       // reuses E after out-proj consumed ao

  const size_t NEED = ((size_t)(y2f + ACT) - (size_t)d_ws);
  bool big = ws_size >= NEED;

  // 1) weight transpose+cast + bias concat
  prep_weights<<<6921, 256, 0, stream>>>(wq, wk, wv, wo, w1, w2, bq, bk, bv, bqkv,
                                         wqT, wkT, wvT, woT, w1T, w2T);

  // 2) LN1 on x1 (= x[...,1])
  ln_kernel<<<8192, 256, 0, stream>>>(x, 2, 1, ln1_g, ln1_b, xln);

  // 3) fused QKV projection (+ direct V^T via aux)  (2-phase, K=768, m-fastest)
  gemm_lds<128, 128, 4, 0><<<dim3(18, 64), 256, 0, stream>>>(
      xln, wqT, bqkv, nullptr, (const float*)vbT, qb, 8192, 2304, 768);

  // 4) attention (fused mid + global split-K)
  attn_fused<<<dim3(78, 12, 2), 256, 0, stream>>>(qb, kb, vbT, rand_attn, aob, partp);
  attn_combine<<<dim3(2, 12, 2), 256, 0, stream>>>(partp, aob);

  if (big) {
    // 5) out-proj + residual(x2) -> y2f contiguous fp32  (2-phase, K=768)
    gemm_lds<128, 128, 5, 0><<<dim3(6, 64), 256, 0, stream>>>(
        aob, woT, bo, x, nullptr, y2f, 8192, 768, 768);
    // 6) LN2 on y2f (contiguous)
    ln_kernel<<<8192, 256, 0, stream>>>(y2f, 1, 0, ln2_g, ln2_b, ln2b);
    // 7) MLP  (both 2-phase; MLP2 K=3072 -> n-fastest)
    gemm_lds<128, 128, 2, 0><<<dim3(24, 64), 256, 0, stream>>>(
        ln2b, w1T, b1, nullptr, nullptr, h1, 8192, 3072, 768);
    gemm_lds<128, 128, 6, 1><<<dim3(6, 64), 256, 0, stream>>>(
        h1, w2T, b2, x, y2f, out, 8192, 768, 3072);
  } else {
    // fallback: interleaved path (all 2-phase)
    gemm_lds<128, 128, 1, 0><<<dim3(6, 64), 256, 0, stream>>>(
        aob, woT, bo, x, nullptr, out, 8192, 768, 768);
    ln_kernel<<<8192, 256, 0, stream>>>((const float*)d_out, 2, 1, ln2_g, ln2_b, ln2b);
    gemm_lds<128, 128, 2, 0><<<dim3(24, 64), 256, 0, stream>>>(
        ln2b, w1T, b1, nullptr, nullptr, h1, 8192, 3072, 768);
    gemm_lds<128, 128, 3, 1><<<dim3(6, 64), 256, 0, stream>>>(
        h1, w2T, b2, x, nullptr, out, 8192, 768, 3072);
  }
}